// Round 1
// baseline (265.211 us; speedup 1.0000x reference)
//
#include <hip/hip_runtime.h>

#define BB 4
#define CH 64
#define HW 65536
#define NN 16384
#define NT 128
#define XPITCH 104
#define W1OFS 0
#define W2OFS 6144
#define W3OFS 10240
#define WFOFS 14336
#define FWS_BYTE 46080
#define PTAB_BYTE 49152
#define PT_ROW 160
#define WS_NEED ((size_t)PTAB_BYTE + (size_t)BB * NN * PT_ROW)

typedef __attribute__((ext_vector_type(8))) short short8;
typedef __attribute__((ext_vector_type(4))) float f32x4;

union frag_u { unsigned short u[8]; short8 v; };
union half_u { uint4 q[2]; unsigned short u[16]; };

static __device__ __forceinline__ unsigned short f2bf(float x) {
    unsigned int u = __float_as_uint(x);
    return (unsigned short)((u + 0x7fffu + ((u >> 16) & 1u)) >> 16);
}
static __device__ __forceinline__ float bf2f(unsigned short h) {
    return __uint_as_float(((unsigned int)h) << 16);
}

// ---------------- prepass: pack weights (bf16) + f32 aux into ws ----------------
// split across 5 blocks (was 1 block = 1 CU = pure latency)
__global__ __launch_bounds__(256) void prep_w(
    const float* __restrict__ w1, const float* __restrict__ b1,
    const float* __restrict__ w2, const float* __restrict__ b2,
    const float* __restrict__ w3, const float* __restrict__ b3,
    const float* __restrict__ wf, const float* __restrict__ bf,
    unsigned short* __restrict__ wpk, float* __restrict__ fws)
{
    const int t = threadIdx.x;
    const int blk = blockIdx.x;
    if (blk == 0) {
        // w1 packed [64][96]; col map: 0-63 <- ref 3..66 (g), 64 <- ref 0 (corr),
        // 65,66 <- 0 (offset handled in f32), 67,68 <- ref 67,68 (flow), 69-95 <- 0
        for (int i = t; i < 64 * 96; i += 256) {
            const int m = i / 96, k = i % 96;
            float v = 0.f;
            if (k < 64) v = w1[m * 69 + 3 + k];
            else if (k == 64) v = w1[m * 69 + 0];
            else if (k == 67) v = w1[m * 69 + 67];
            else if (k == 68) v = w1[m * 69 + 68];
            wpk[W1OFS + i] = f2bf(v);
        }
    } else if (blk == 1) {
        for (int i = t; i < 64 * 64; i += 256) wpk[W2OFS + i] = f2bf(w2[i]);
    } else if (blk == 2) {
        for (int i = t; i < 64 * 64; i += 256) wpk[W3OFS + i] = f2bf(w3[i]);
    } else if (blk == 3) {
        for (int i = t; i < 64 * 128; i += 256) wpk[WFOFS + i] = f2bf(wf[i]);
    } else if (t < 64) {
        fws[t]       = b1[t];
        fws[64 + t]  = b2[t];
        fws[128 + t] = b3[t];
        fws[192 + t] = bf[t];
        fws[256 + t] = w1[t * 69 + 1];   // offset-x column (f32 path)
        fws[320 + t] = w1[t * 69 + 2];   // offset-y column
    }
}

// ---------------- prepass: point table [B][N] row = 64 bf16 g + pad + 4 f32 ----------------
// 1024 blocks, 16 channels/thread (was 256 blocks x 64 ch/thread: latency-bound)
__global__ __launch_bounds__(256) void prep_t(
    const float* __restrict__ xy, const float* __restrict__ f3d,
    const float* __restrict__ lf3d, char* __restrict__ pt)
{
    const int t = threadIdx.x;
    const int cq = t >> 6;                 // channel quarter 0..3
    const int l = t & 63;
    const int gn = blockIdx.x * 64 + l;
    const int b = blockIdx.y;
    half_u r;
#pragma unroll
    for (int i = 0; i < 16; i++)
        r.u[i] = f2bf(f3d[(size_t)(b * CH + cq * 16 + i) * NN + gn]);
    char* row = pt + ((size_t)b * NN + gn) * PT_ROW;
    uint4* rq = (uint4*)row;
    rq[2 * cq] = r.q[0];
    rq[2 * cq + 1] = r.q[1];
    if (cq == 0) {
        float4 e;
        e.x = xy[(size_t)(b * 2 + 0) * NN + gn];
        e.y = xy[(size_t)(b * 2 + 1) * NN + gn];
        e.z = lf3d[(size_t)(b * 2 + 0) * NN + gn];
        e.w = lf3d[(size_t)(b * 2 + 1) * NN + gn];
        *(float4*)(row + 144) = e;
    }
}

// ---------------- MFMA layer core (wave owns 16 rows: nr = rowb + ln) ----------------
template<int KT, int KROW, bool LO>
static __device__ __forceinline__ void layer_mfma(
    const unsigned short* __restrict__ wrow,
    const unsigned short* Xh, const unsigned short* Xl,
    int rowb, int ln, int q, f32x4 acc[4])
{
#pragma unroll
    for (int kt = 0; kt < KT; kt++) {
        const int kcol = kt * 32 + q * 8;
        short8 A[4];
#pragma unroll
        for (int mi = 0; mi < 4; mi++)
            A[mi] = *(const short8*)(wrow + (mi * 16 + ln) * KROW + kcol);
        const int nr = rowb + ln;
        short8 bh = *(const short8*)(Xh + nr * XPITCH + kcol);
        short8 bl = bh;
        if (LO) bl = *(const short8*)(Xl + nr * XPITCH + kcol);
#pragma unroll
        for (int mi = 0; mi < 4; mi++) {
            acc[mi] = __builtin_amdgcn_mfma_f32_16x16x32_bf16(A[mi], bh, acc[mi], 0, 0, 0);
            if (LO)
                acc[mi] = __builtin_amdgcn_mfma_f32_16x16x32_bf16(A[mi], bl, acc[mi], 0, 0, 0);
        }
    }
}

static __device__ __forceinline__ void zero_acc(f32x4 acc[4]) {
#pragma unroll
    for (int mi = 0; mi < 4; mi++)
#pragma unroll
        for (int r = 0; r < 4; r++) acc[mi][r] = 0.f;
}

// epilogue: leaky(acc + bias [+ f32 offset fix]) -> X hi/lo (wave-private rows)
static __device__ __forceinline__ void epi_x(
    f32x4 acc[4], const float* __restrict__ fws, int bofs, bool off_fix,
    const float* offsp, unsigned short* Xh, unsigned short* Xl,
    int rowb, int ln, int q)
{
    const int nr = rowb + ln;
    float ox = 0.f, oy = 0.f;
    if (off_fix) { ox = offsp[nr]; oy = offsp[NT + nr]; }
#pragma unroll
    for (int mi = 0; mi < 4; mi++) {
        const float4 bias = *(const float4*)(fws + bofs + mi * 16 + q * 4);
        float4 wox = bias, woy = bias;
        if (off_fix) {
            wox = *(const float4*)(fws + 256 + mi * 16 + q * 4);
            woy = *(const float4*)(fws + 320 + mi * 16 + q * 4);
        }
        unsigned int hh0 = 0, hh1 = 0, ll0 = 0, ll1 = 0;
#pragma unroll
        for (int r = 0; r < 4; r++) {
            float a = acc[mi][r] + ((const float*)&bias)[r];
            if (off_fix) a += ((const float*)&wox)[r] * ox + ((const float*)&woy)[r] * oy;
            a = fmaxf(a, 0.1f * a);
            const unsigned short hb = f2bf(a);
            const unsigned short lb = f2bf(a - bf2f(hb));
            if (r == 0) { hh0 = hb; ll0 = lb; }
            if (r == 1) { hh0 |= ((unsigned)hb) << 16; ll0 |= ((unsigned)lb) << 16; }
            if (r == 2) { hh1 = hb; ll1 = lb; }
            if (r == 3) { hh1 |= ((unsigned)hb) << 16; ll1 |= ((unsigned)lb) << 16; }
        }
        *(uint2*)&Xh[nr * XPITCH + mi * 16 + q * 4] = make_uint2(hh0, hh1);
        *(uint2*)&Xl[nr * XPITCH + mi * 16 + q * 4] = make_uint2(ll0, ll1);
    }
}

// ---------------- main fused kernel: 512 threads (8 waves), 2 blocks/CU = 4 waves/SIMD ----------------
__global__ __launch_bounds__(512, 4) void fuse(
    const float* __restrict__ feat2d, const float* __restrict__ lf2d,
    const int* __restrict__ nn,
    const unsigned short* __restrict__ wpk, const float* __restrict__ fws,
    const char* __restrict__ ptab,
    float* __restrict__ out)
{
    __shared__ unsigned short Xhi[NT * XPITCH];
    __shared__ unsigned short Xlo[NT * XPITCH];
    __shared__ float corrP[4 * NT];
    __shared__ float offsS[2 * NT];
    __shared__ float fcfS[2 * NT];
    __shared__ int idxL[NT];

    const int tid = threadIdx.x;
    const int w = tid >> 6, lane = tid & 63;
    const int q = lane >> 4, ln = lane & 15;
    const int b = blockIdx.y;
    const int p0 = blockIdx.x * NT;
    const int rowb = 16 * w;   // wave-private row range [rowb, rowb+16)

    if (tid < NT) idxL[tid] = nn[(size_t)b * HW + p0 + tid];
    __syncthreads();

    { // stage 0: thread = (pixel n, channel quarter cq)
        const int cq = w & 3;
        const int n = (w >> 2) * 64 + lane;
        const int p = p0 + n;
        const int idx = idxL[n];
        const char* prow = ptab + ((size_t)b * NN + idx) * PT_ROW;
        half_u g;
        g.q[0] = ((const uint4*)prow)[2 * cq];
        g.q[1] = ((const uint4*)prow)[2 * cq + 1];
        float ca = 0.f;
#pragma unroll
        for (int i = 0; i < 16; i++) {
            const int c = cq * 16 + i;
            const float f = feat2d[(size_t)(b * CH + c) * HW + p];
            ca += f * bf2f(g.u[i]);
        }
        corrP[cq * NT + n] = ca;
        uint4* xp = (uint4*)&Xhi[n * XPITCH + cq * 16];
        xp[0] = g.q[0];
        xp[1] = g.q[1];
        if (cq == 0) {
            const float4 e = *(const float4*)(prow + 144);
            offsS[n] = e.x - (float)(p & 255);
            offsS[NT + n] = e.y - (float)(p >> 8);
            fcfS[n] = e.z - lf2d[(size_t)(b * 2 + 0) * HW + p];
            fcfS[NT + n] = e.w - lf2d[(size_t)(b * 2 + 1) * HW + p];
        }
    }
    __syncthreads();
    if (w < 2) { // tail cols 64..95: corr, 0, 0, fcx, fcy, zeros
        const int n = w * 64 + lane;
        const float corr = (corrP[n] + corrP[NT + n] + corrP[2 * NT + n] + corrP[3 * NT + n]) * (1.0f / 64.0f);
        const unsigned short chh = f2bf(corr);
        const unsigned short xhh = f2bf(fcfS[n]);
        const unsigned short yhh = f2bf(fcfS[NT + n]);
        uint4* tp = (uint4*)&Xhi[n * XPITCH + 64];
        tp[0] = make_uint4((unsigned)chh, ((unsigned)xhh) << 16, (unsigned)yhh, 0u);
        tp[1] = make_uint4(0, 0, 0, 0);
        tp[2] = make_uint4(0, 0, 0, 0);
        tp[3] = make_uint4(0, 0, 0, 0);
    }
    __syncthreads();

    f32x4 acc[4];
    // L1 (K=96, X hi only; offsets via f32 rank-2 fix)
    zero_acc(acc);
    layer_mfma<3, 96, false>(wpk + W1OFS, Xhi, Xlo, rowb, ln, q, acc);
    epi_x(acc, fws, 0, true, offsS, Xhi, Xlo, rowb, ln, q);
    // L2
    zero_acc(acc);
    layer_mfma<2, 64, true>(wpk + W2OFS, Xhi, Xlo, rowb, ln, q, acc);
    epi_x(acc, fws, 64, false, offsS, Xhi, Xlo, rowb, ln, q);
    // L3
    zero_acc(acc);
    layer_mfma<2, 64, true>(wpk + W3OFS, Xhi, Xlo, rowb, ln, q, acc);
    epi_x(acc, fws, 128, false, offsS, Xhi, Xlo, rowb, ln, q);
    // Lf: k 0-63 = x3 (LDS, hi+lo), k 64-127 = feat2d (global, L2-hot, hi only)
    zero_acc(acc);
    layer_mfma<2, 128, true>(wpk + WFOFS, Xhi, Xlo, rowb, ln, q, acc);
#pragma unroll
    for (int kt = 2; kt < 4; kt++) {
        const int kcol = kt * 32 + q * 8;
        short8 A[4];
#pragma unroll
        for (int mi = 0; mi < 4; mi++)
            A[mi] = *(const short8*)(wpk + WFOFS + (mi * 16 + ln) * 128 + kcol);
        frag_u fh;
#pragma unroll
        for (int j = 0; j < 8; j++) {
            const int c = (kt - 2) * 32 + q * 8 + j;
            const float v = feat2d[(size_t)(b * CH + c) * HW + p0 + rowb + ln];
            fh.u[j] = f2bf(v);
        }
#pragma unroll
        for (int mi = 0; mi < 4; mi++)
            acc[mi] = __builtin_amdgcn_mfma_f32_16x16x32_bf16(A[mi], fh.v, acc[mi], 0, 0, 0);
    }
    // final epilogue -> out f32
#pragma unroll
    for (int mi = 0; mi < 4; mi++) {
        const float4 bias = *(const float4*)(fws + 192 + mi * 16 + q * 4);
#pragma unroll
        for (int r = 0; r < 4; r++) {
            float a = acc[mi][r] + ((const float*)&bias)[r];
            a = fmaxf(a, 0.1f * a);
            const int m = mi * 16 + q * 4 + r;
            out[(size_t)(b * CH + m) * HW + p0 + rowb + ln] = a;
        }
    }
}

// ---------------- fallback (R4, passed): used only if ws too small ----------------
__global__ __launch_bounds__(256) void fuse_slow(
    const float* __restrict__ feat2d, const float* __restrict__ lf2d,
    const float* __restrict__ xy, const float* __restrict__ feat3d,
    const float* __restrict__ lf3d, const int* __restrict__ nn,
    const float* __restrict__ w1, const float* __restrict__ b1,
    const float* __restrict__ w2, const float* __restrict__ b2,
    const float* __restrict__ w3, const float* __restrict__ b3,
    const float* __restrict__ wf, const float* __restrict__ bfv,
    float* __restrict__ out)
{
    const int p = blockIdx.x * 256 + threadIdx.x;
    const int b = blockIdx.y;
    const int idx = nn[(size_t)b * HW + p];
    const float* f3 = feat3d + (size_t)b * CH * NN + idx;
    float g[CH];
#pragma unroll
    for (int c = 0; c < CH; c++) g[c] = f3[(size_t)c * NN];
    const float fl3x = lf3d[(size_t)(b * 2 + 0) * NN + idx];
    const float fl3y = lf3d[(size_t)(b * 2 + 1) * NN + idx];
    const float xyx = xy[(size_t)(b * 2 + 0) * NN + idx];
    const float xyy = xy[(size_t)(b * 2 + 1) * NN + idx];
    const float* f2p = feat2d + (size_t)b * CH * HW + p;
    float corr = 0.f;
#pragma unroll
    for (int c = 0; c < CH; c++) corr += f2p[(size_t)c * HW] * g[c];
    corr *= (1.f / 64.f);
    float xin[69];
    xin[0] = corr;
    xin[1] = xyx - (float)(p & 255);
    xin[2] = xyy - (float)(p >> 8);
#pragma unroll
    for (int c = 0; c < CH; c++) xin[3 + c] = g[c];
    xin[67] = fl3x - lf2d[(size_t)(b * 2 + 0) * HW + p];
    xin[68] = fl3y - lf2d[(size_t)(b * 2 + 1) * HW + p];
    float x1[64], x2[64], x3[64], accv[64];
#pragma unroll
    for (int o = 0; o < 64; o++) {
        float a = b1[o];
#pragma unroll
        for (int k = 0; k < 69; k++) a += w1[o * 69 + k] * xin[k];
        x1[o] = (a >= 0.f) ? a : 0.1f * a;
    }
#pragma unroll
    for (int o = 0; o < 64; o++) {
        float a = b2[o];
#pragma unroll
        for (int k = 0; k < 64; k++) a += w2[o * 64 + k] * x1[k];
        x2[o] = (a >= 0.f) ? a : 0.1f * a;
    }
#pragma unroll
    for (int o = 0; o < 64; o++) {
        float a = b3[o];
#pragma unroll
        for (int k = 0; k < 64; k++) a += w3[o * 64 + k] * x2[k];
        x3[o] = (a >= 0.f) ? a : 0.1f * a;
    }
#pragma unroll
    for (int o = 0; o < 64; o++) {
        float a = bfv[o];
#pragma unroll
        for (int k = 0; k < 64; k++) a += wf[o * 128 + k] * x3[k];
        accv[o] = a;
    }
#pragma unroll
    for (int k = 0; k < 64; k++) {
        const float f = f2p[(size_t)k * HW];
#pragma unroll
        for (int o = 0; o < 64; o++) accv[o] += wf[o * 128 + 64 + k] * f;
    }
#pragma unroll
    for (int o = 0; o < 64; o++) {
        float a = accv[o];
        a = (a >= 0.f) ? a : 0.1f * a;
        out[(size_t)(b * CH + o) * HW + p] = a;
    }
}

extern "C" void kernel_launch(void* const* d_in, const int* in_sizes, int n_in,
                              void* d_out, int out_size, void* d_ws, size_t ws_size,
                              hipStream_t stream)
{
    const float* xy   = (const float*)d_in[0];
    const float* f2d  = (const float*)d_in[1];
    const float* f3d  = (const float*)d_in[2];
    const float* lf2d = (const float*)d_in[3];
    const float* lf3d = (const float*)d_in[4];
    const int*   nn   = (const int*)d_in[5];
    const float* w1 = (const float*)d_in[6];
    const float* b1 = (const float*)d_in[7];
    const float* w2 = (const float*)d_in[8];
    const float* b2 = (const float*)d_in[9];
    const float* w3 = (const float*)d_in[10];
    const float* b3 = (const float*)d_in[11];
    const float* wf = (const float*)d_in[12];
    const float* bf = (const float*)d_in[13];

    if (ws_size >= WS_NEED) {
        unsigned short* wpk = (unsigned short*)d_ws;
        float* fws = (float*)((char*)d_ws + FWS_BYTE);
        char* pt = (char*)d_ws + PTAB_BYTE;
        prep_w<<<dim3(5), 256, 0, stream>>>(w1, b1, w2, b2, w3, b3, wf, bf, wpk, fws);
        prep_t<<<dim3(NN / 64, BB), 256, 0, stream>>>(xy, f3d, lf3d, pt);
        fuse<<<dim3(HW / NT, BB), 512, 0, stream>>>(f2d, lf2d, nn, wpk, fws, pt, (float*)d_out);
    } else {
        fuse_slow<<<dim3(HW / 256, BB), 256, 0, stream>>>(f2d, lf2d, xy, f3d, lf3d, nn,
                                                          w1, b1, w2, b2, w3, b3, wf, bf,
                                                          (float*)d_out);
    }
}

// Round 2
// 237.416 us; speedup vs baseline: 1.1171x; 1.1171x over previous
//
#include <hip/hip_runtime.h>

#define BB 4
#define CH 64
#define HW 65536
#define NN 16384
#define NT 128
#define XPITCH 104
#define LPITCH 72
#define W1OFS 0
#define W2OFS 6144
#define W3OFS 10240
#define WFOFS 14336
#define FWS_BYTE 46080
#define PTAB_BYTE 49152
#define PT_ROW 160
#define WS_NEED ((size_t)PTAB_BYTE + (size_t)BB * NN * PT_ROW)

typedef __attribute__((ext_vector_type(8))) short short8;
typedef __attribute__((ext_vector_type(4))) float f32x4;

union frag_u { unsigned short u[8]; short8 v; };
union row_u  { uint4 q[4]; unsigned short u[32]; };
union half_u { uint4 q[2]; unsigned short u[16]; };

static __device__ __forceinline__ unsigned short f2bf(float x) {
    unsigned int u = __float_as_uint(x);
    return (unsigned short)((u + 0x7fffu + ((u >> 16) & 1u)) >> 16);
}
static __device__ __forceinline__ float bf2f(unsigned short h) {
    return __uint_as_float(((unsigned int)h) << 16);
}

// ---------------- prepass: pack weights (bf16) + f32 aux into ws ----------------
__global__ __launch_bounds__(256) void prep_w(
    const float* __restrict__ w1, const float* __restrict__ b1,
    const float* __restrict__ w2, const float* __restrict__ b2,
    const float* __restrict__ w3, const float* __restrict__ b3,
    const float* __restrict__ wf, const float* __restrict__ bf,
    unsigned short* __restrict__ wpk, float* __restrict__ fws)
{
    const int t = threadIdx.x;
    const int blk = blockIdx.x;
    if (blk == 0) {
        // w1 packed [64][96]; col map: 0-63 <- ref 3..66 (g), 64 <- ref 0 (corr),
        // 65,66 <- 0 (offset handled in f32), 67,68 <- ref 67,68 (flow), 69-95 <- 0
        for (int i = t; i < 64 * 96; i += 256) {
            const int m = i / 96, k = i % 96;
            float v = 0.f;
            if (k < 64) v = w1[m * 69 + 3 + k];
            else if (k == 64) v = w1[m * 69 + 0];
            else if (k == 67) v = w1[m * 69 + 67];
            else if (k == 68) v = w1[m * 69 + 68];
            wpk[W1OFS + i] = f2bf(v);
        }
    } else if (blk == 1) {
        for (int i = t; i < 64 * 64; i += 256) wpk[W2OFS + i] = f2bf(w2[i]);
    } else if (blk == 2) {
        for (int i = t; i < 64 * 64; i += 256) wpk[W3OFS + i] = f2bf(w3[i]);
    } else if (blk == 3) {
        for (int i = t; i < 64 * 128; i += 256) wpk[WFOFS + i] = f2bf(wf[i]);
    } else if (t < 64) {
        fws[t]       = b1[t];
        fws[64 + t]  = b2[t];
        fws[128 + t] = b3[t];
        fws[192 + t] = bf[t];
        fws[256 + t] = w1[t * 69 + 1];   // offset-x column (f32 path)
        fws[320 + t] = w1[t * 69 + 2];   // offset-y column
    }
}

// ---------------- prepass: point table [B][N] row = 64 bf16 g + pad + 4 f32 ----------------
__global__ __launch_bounds__(256) void prep_t(
    const float* __restrict__ xy, const float* __restrict__ f3d,
    const float* __restrict__ lf3d, char* __restrict__ pt)
{
    const int t = threadIdx.x;
    const int cq = t >> 6;                 // channel quarter 0..3
    const int l = t & 63;
    const int gn = blockIdx.x * 64 + l;
    const int b = blockIdx.y;
    half_u r;
#pragma unroll
    for (int i = 0; i < 16; i++)
        r.u[i] = f2bf(f3d[(size_t)(b * CH + cq * 16 + i) * NN + gn]);
    char* row = pt + ((size_t)b * NN + gn) * PT_ROW;
    uint4* rq = (uint4*)row;
    rq[2 * cq] = r.q[0];
    rq[2 * cq + 1] = r.q[1];
    if (cq == 0) {
        float4 e;
        e.x = xy[(size_t)(b * 2 + 0) * NN + gn];
        e.y = xy[(size_t)(b * 2 + 1) * NN + gn];
        e.z = lf3d[(size_t)(b * 2 + 0) * NN + gn];
        e.w = lf3d[(size_t)(b * 2 + 1) * NN + gn];
        *(float4*)(row + 144) = e;
    }
}

// ---------------- MFMA layer core (wave owns rows [32w, 32w+32), acc[4][2]) ----------------
template<int KT, int KROW, bool LO>
static __device__ __forceinline__ void layer_mfma(
    const unsigned short* __restrict__ wrow,
    const unsigned short* Xh, const unsigned short* Xl,
    int w, int ln, int q, f32x4 acc[4][2])
{
#pragma unroll
    for (int kt = 0; kt < KT; kt++) {
        const int kcol = kt * 32 + q * 8;
        short8 A[4];
#pragma unroll
        for (int mi = 0; mi < 4; mi++)
            A[mi] = *(const short8*)(wrow + (mi * 16 + ln) * KROW + kcol);
#pragma unroll
        for (int ni = 0; ni < 2; ni++) {
            const int nr = 32 * w + ni * 16 + ln;
            short8 bh = *(const short8*)(Xh + nr * XPITCH + kcol);
            short8 bl = bh;
            if (LO) bl = *(const short8*)(Xl + nr * LPITCH + kcol);
#pragma unroll
            for (int mi = 0; mi < 4; mi++) {
                acc[mi][ni] = __builtin_amdgcn_mfma_f32_16x16x32_bf16(A[mi], bh, acc[mi][ni], 0, 0, 0);
                if (LO)
                    acc[mi][ni] = __builtin_amdgcn_mfma_f32_16x16x32_bf16(A[mi], bl, acc[mi][ni], 0, 0, 0);
            }
        }
    }
}

static __device__ __forceinline__ void zero_acc(f32x4 acc[4][2]) {
#pragma unroll
    for (int mi = 0; mi < 4; mi++)
#pragma unroll
        for (int ni = 0; ni < 2; ni++)
#pragma unroll
            for (int r = 0; r < 4; r++) acc[mi][ni][r] = 0.f;
}

// epilogue: leaky(acc + bias [+ f32 offset fix]) -> X hi/lo (wave-private rows)
static __device__ __forceinline__ void epi_x(
    f32x4 acc[4][2], const float* __restrict__ fws, int bofs, bool off_fix,
    const float* offsp, unsigned short* Xh, unsigned short* Xl,
    int w, int ln, int q)
{
#pragma unroll
    for (int mi = 0; mi < 4; mi++) {
        const float4 bias = *(const float4*)(fws + bofs + mi * 16 + q * 4);
        float4 wox = bias, woy = bias;
        if (off_fix) {
            wox = *(const float4*)(fws + 256 + mi * 16 + q * 4);
            woy = *(const float4*)(fws + 320 + mi * 16 + q * 4);
        }
#pragma unroll
        for (int ni = 0; ni < 2; ni++) {
            const int nr = 32 * w + ni * 16 + ln;
            float ox = 0.f, oy = 0.f;
            if (off_fix) { ox = offsp[nr]; oy = offsp[NT + nr]; }
            unsigned int hh0 = 0, hh1 = 0, ll0 = 0, ll1 = 0;
#pragma unroll
            for (int r = 0; r < 4; r++) {
                float a = acc[mi][ni][r] + ((const float*)&bias)[r];
                if (off_fix) a += ((const float*)&wox)[r] * ox + ((const float*)&woy)[r] * oy;
                a = fmaxf(a, 0.1f * a);
                const unsigned short hb = f2bf(a);
                const unsigned short lb = f2bf(a - bf2f(hb));
                if (r == 0) { hh0 = hb; ll0 = lb; }
                if (r == 1) { hh0 |= ((unsigned)hb) << 16; ll0 |= ((unsigned)lb) << 16; }
                if (r == 2) { hh1 = hb; ll1 = lb; }
                if (r == 3) { hh1 |= ((unsigned)hb) << 16; ll1 |= ((unsigned)lb) << 16; }
            }
            *(uint2*)&Xh[nr * XPITCH + mi * 16 + q * 4] = make_uint2(hh0, hh1);
            *(uint2*)&Xl[nr * LPITCH + mi * 16 + q * 4] = make_uint2(ll0, ll1);
        }
    }
}

// ---------------- main fused kernel: 256 thr, ZERO block barriers, 3 blocks/CU ----------------
// Each wave owns pixels [32w, 32w+32): all LDS traffic is wave-private, so waves run as
// 12 independent streams/CU (3 blocks x 4 waves) and one wave's random-gather latency is
// hidden under another wave's MFMA/epilogue.
__global__ __launch_bounds__(256, 3) void fuse(
    const float* __restrict__ feat2d, const float* __restrict__ lf2d,
    const int* __restrict__ nn,
    const unsigned short* __restrict__ wpk, const float* __restrict__ fws,
    const char* __restrict__ ptab,
    float* __restrict__ out)
{
    __shared__ unsigned short Xhi[NT * XPITCH];   // 26624 B, K cols 0..95 (+pad)
    __shared__ unsigned short Xlo[NT * LPITCH];   // 18432 B, K cols 0..63 (+pad)
    __shared__ float offsS[2 * NT];               //  1024 B
    // total 46080 B -> 3 blocks/CU

    const int tid = threadIdx.x;
    const int w = tid >> 6, lane = tid & 63;
    const int q = lane >> 4, ln = lane & 15;
    const int b = blockIdx.y;
    const int p0 = blockIdx.x * NT;

    { // stage 0 (wave-private): lane = (cp = channel half, j = pixel-in-wave)
        const int cp = lane >> 5, j = lane & 31;
        const int n = 32 * w + j;
        const int p = p0 + n;
        const int idx = nn[(size_t)b * HW + p];
        const char* prow = ptab + ((size_t)b * NN + idx) * PT_ROW;
        row_u g;
#pragma unroll
        for (int k = 0; k < 4; k++) g.q[k] = ((const uint4*)prow)[cp * 4 + k];
        float ca = 0.f;
#pragma unroll
        for (int i = 0; i < 32; i++) {
            const int c = cp * 32 + i;
            ca += feat2d[(size_t)(b * CH + c) * HW + p] * bf2f(g.u[i]);
        }
        uint4* xp = (uint4*)&Xhi[n * XPITCH + cp * 32];
#pragma unroll
        for (int k = 0; k < 4; k++) xp[k] = g.q[k];
        ca += __shfl_xor(ca, 32);        // combine the two channel-halves in-wave
        if (cp == 0) {
            const float4 e = *(const float4*)(prow + 144);
            offsS[n] = e.x - (float)(p & 255);
            offsS[NT + n] = e.y - (float)(p >> 8);
            const float fcx = e.z - lf2d[(size_t)(b * 2 + 0) * HW + p];
            const float fcy = e.w - lf2d[(size_t)(b * 2 + 1) * HW + p];
            const unsigned short chh = f2bf(ca * (1.0f / 64.0f));
            const unsigned short xhh = f2bf(fcx);
            const unsigned short yhh = f2bf(fcy);
            // tail cols 64..95: corr, 0, 0, fcx, fcy, zeros
            uint4* tp = (uint4*)&Xhi[n * XPITCH + 64];
            tp[0] = make_uint4((unsigned)chh, ((unsigned)xhh) << 16, (unsigned)yhh, 0u);
            tp[1] = make_uint4(0, 0, 0, 0);
            tp[2] = make_uint4(0, 0, 0, 0);
            tp[3] = make_uint4(0, 0, 0, 0);
        }
    }
    // no __syncthreads: all LDS deps are intra-wave (ordered via lgkmcnt)

    f32x4 acc[4][2];
    // L1 (K=96, X hi only; offsets via f32 rank-2 fix)
    zero_acc(acc);
    layer_mfma<3, 96, false>(wpk + W1OFS, Xhi, Xlo, w, ln, q, acc);
    epi_x(acc, fws, 0, true, offsS, Xhi, Xlo, w, ln, q);
    // L2
    zero_acc(acc);
    layer_mfma<2, 64, true>(wpk + W2OFS, Xhi, Xlo, w, ln, q, acc);
    epi_x(acc, fws, 64, false, offsS, Xhi, Xlo, w, ln, q);
    // L3
    zero_acc(acc);
    layer_mfma<2, 64, true>(wpk + W3OFS, Xhi, Xlo, w, ln, q, acc);
    epi_x(acc, fws, 128, false, offsS, Xhi, Xlo, w, ln, q);
    // Lf: k 0-63 = x3 (LDS, hi+lo), k 64-127 = feat2d (global, L2-hot, hi only)
    zero_acc(acc);
    layer_mfma<2, 128, true>(wpk + WFOFS, Xhi, Xlo, w, ln, q, acc);
#pragma unroll
    for (int kt = 2; kt < 4; kt++) {
        const int kcol = kt * 32 + q * 8;
        short8 A[4];
#pragma unroll
        for (int mi = 0; mi < 4; mi++)
            A[mi] = *(const short8*)(wpk + WFOFS + (mi * 16 + ln) * 128 + kcol);
#pragma unroll
        for (int ni = 0; ni < 2; ni++) {
            frag_u fh;
#pragma unroll
            for (int j = 0; j < 8; j++) {
                const int c = (kt - 2) * 32 + q * 8 + j;
                const float v = feat2d[(size_t)(b * CH + c) * HW + p0 + 32 * w + ni * 16 + ln];
                fh.u[j] = f2bf(v);
            }
#pragma unroll
            for (int mi = 0; mi < 4; mi++)
                acc[mi][ni] = __builtin_amdgcn_mfma_f32_16x16x32_bf16(A[mi], fh.v, acc[mi][ni], 0, 0, 0);
        }
    }
    // final epilogue -> out f32
#pragma unroll
    for (int mi = 0; mi < 4; mi++) {
        const float4 bias = *(const float4*)(fws + 192 + mi * 16 + q * 4);
#pragma unroll
        for (int ni = 0; ni < 2; ni++) {
#pragma unroll
            for (int r = 0; r < 4; r++) {
                float a = acc[mi][ni][r] + ((const float*)&bias)[r];
                a = fmaxf(a, 0.1f * a);
                const int m = mi * 16 + q * 4 + r;
                out[(size_t)(b * CH + m) * HW + p0 + 32 * w + ni * 16 + ln] = a;
            }
        }
    }
}

// ---------------- fallback (R4, passed): used only if ws too small ----------------
__global__ __launch_bounds__(256) void fuse_slow(
    const float* __restrict__ feat2d, const float* __restrict__ lf2d,
    const float* __restrict__ xy, const float* __restrict__ feat3d,
    const float* __restrict__ lf3d, const int* __restrict__ nn,
    const float* __restrict__ w1, const float* __restrict__ b1,
    const float* __restrict__ w2, const float* __restrict__ b2,
    const float* __restrict__ w3, const float* __restrict__ b3,
    const float* __restrict__ wf, const float* __restrict__ bfv,
    float* __restrict__ out)
{
    const int p = blockIdx.x * 256 + threadIdx.x;
    const int b = blockIdx.y;
    const int idx = nn[(size_t)b * HW + p];
    const float* f3 = feat3d + (size_t)b * CH * NN + idx;
    float g[CH];
#pragma unroll
    for (int c = 0; c < CH; c++) g[c] = f3[(size_t)c * NN];
    const float fl3x = lf3d[(size_t)(b * 2 + 0) * NN + idx];
    const float fl3y = lf3d[(size_t)(b * 2 + 1) * NN + idx];
    const float xyx = xy[(size_t)(b * 2 + 0) * NN + idx];
    const float xyy = xy[(size_t)(b * 2 + 1) * NN + idx];
    const float* f2p = feat2d + (size_t)b * CH * HW + p;
    float corr = 0.f;
#pragma unroll
    for (int c = 0; c < CH; c++) corr += f2p[(size_t)c * HW] * g[c];
    corr *= (1.f / 64.f);
    float xin[69];
    xin[0] = corr;
    xin[1] = xyx - (float)(p & 255);
    xin[2] = xyy - (float)(p >> 8);
#pragma unroll
    for (int c = 0; c < CH; c++) xin[3 + c] = g[c];
    xin[67] = fl3x - lf2d[(size_t)(b * 2 + 0) * HW + p];
    xin[68] = fl3y - lf2d[(size_t)(b * 2 + 1) * HW + p];
    float x1[64], x2[64], x3[64], accv[64];
#pragma unroll
    for (int o = 0; o < 64; o++) {
        float a = b1[o];
#pragma unroll
        for (int k = 0; k < 69; k++) a += w1[o * 69 + k] * xin[k];
        x1[o] = (a >= 0.f) ? a : 0.1f * a;
    }
#pragma unroll
    for (int o = 0; o < 64; o++) {
        float a = b2[o];
#pragma unroll
        for (int k = 0; k < 64; k++) a += w2[o * 64 + k] * x1[k];
        x2[o] = (a >= 0.f) ? a : 0.1f * a;
    }
#pragma unroll
    for (int o = 0; o < 64; o++) {
        float a = b3[o];
#pragma unroll
        for (int k = 0; k < 64; k++) a += w3[o * 64 + k] * x2[k];
        x3[o] = (a >= 0.f) ? a : 0.1f * a;
    }
#pragma unroll
    for (int o = 0; o < 64; o++) {
        float a = bfv[o];
#pragma unroll
        for (int k = 0; k < 64; k++) a += wf[o * 128 + k] * x3[k];
        accv[o] = a;
    }
#pragma unroll
    for (int k = 0; k < 64; k++) {
        const float f = f2p[(size_t)k * HW];
#pragma unroll
        for (int o = 0; o < 64; o++) accv[o] += wf[o * 128 + 64 + k] * f;
    }
#pragma unroll
    for (int o = 0; o < 64; o++) {
        float a = accv[o];
        a = (a >= 0.f) ? a : 0.1f * a;
        out[(size_t)(b * CH + o) * HW + p] = a;
    }
}

extern "C" void kernel_launch(void* const* d_in, const int* in_sizes, int n_in,
                              void* d_out, int out_size, void* d_ws, size_t ws_size,
                              hipStream_t stream)
{
    const float* xy   = (const float*)d_in[0];
    const float* f2d  = (const float*)d_in[1];
    const float* f3d  = (const float*)d_in[2];
    const float* lf2d = (const float*)d_in[3];
    const float* lf3d = (const float*)d_in[4];
    const int*   nn   = (const int*)d_in[5];
    const float* w1 = (const float*)d_in[6];
    const float* b1 = (const float*)d_in[7];
    const float* w2 = (const float*)d_in[8];
    const float* b2 = (const float*)d_in[9];
    const float* w3 = (const float*)d_in[10];
    const float* b3 = (const float*)d_in[11];
    const float* wf = (const float*)d_in[12];
    const float* bf = (const float*)d_in[13];

    if (ws_size >= WS_NEED) {
        unsigned short* wpk = (unsigned short*)d_ws;
        float* fws = (float*)((char*)d_ws + FWS_BYTE);
        char* pt = (char*)d_ws + PTAB_BYTE;
        prep_w<<<dim3(5), 256, 0, stream>>>(w1, b1, w2, b2, w3, b3, wf, bf, wpk, fws);
        prep_t<<<dim3(NN / 64, BB), 256, 0, stream>>>(xy, f3d, lf3d, pt);
        fuse<<<dim3(HW / NT, BB), 256, 0, stream>>>(f2d, lf2d, nn, wpk, fws, pt, (float*)d_out);
    } else {
        fuse_slow<<<dim3(HW / 256, BB), 256, 0, stream>>>(f2d, lf2d, xy, f3d, lf3d, nn,
                                                          w1, b1, w2, b2, w3, b3, wf, bf,
                                                          (float*)d_out);
    }
}

// Round 3
// 227.126 us; speedup vs baseline: 1.1677x; 1.0453x over previous
//
#include <hip/hip_runtime.h>

#define BB 4
#define CH 64
#define HW 65536
#define NN 16384
#define NT 128
#define XPITCH 72
#define LPITCH 72
#define W1OFS 0
#define W2OFS 4096
#define W3OFS 8192
#define WFOFS 12288
#define FWS_BYTE 46080
#define PTAB_BYTE 49152
#define PT_ROW 160
#define WS_NEED ((size_t)PTAB_BYTE + (size_t)BB * NN * PT_ROW)

typedef __attribute__((ext_vector_type(8))) short short8;
typedef __attribute__((ext_vector_type(4))) float f32x4;

union frag_u { unsigned short u[8]; short8 v; };
union row_u  { uint4 q[4]; unsigned short u[32]; };
union half_u { uint4 q[2]; unsigned short u[16]; };

static __device__ __forceinline__ unsigned short f2bf(float x) {
    unsigned int u = __float_as_uint(x);
    return (unsigned short)((u + 0x7fffu + ((u >> 16) & 1u)) >> 16);
}
static __device__ __forceinline__ float bf2f(unsigned short h) {
    return __uint_as_float(((unsigned int)h) << 16);
}

// ---------------- prepass: pack weights (bf16) + f32 aux into ws ----------------
// fws layout (f32): 0 b1 | 64 b2 | 128 b3 | 192 bf | 256 w_ox | 320 w_oy |
//                   384 w_corr | 448 w_fx | 512 w_fy
__global__ __launch_bounds__(256) void prep_w(
    const float* __restrict__ w1, const float* __restrict__ b1,
    const float* __restrict__ w2, const float* __restrict__ b2,
    const float* __restrict__ w3, const float* __restrict__ b3,
    const float* __restrict__ wf, const float* __restrict__ bf,
    unsigned short* __restrict__ wpk, float* __restrict__ fws)
{
    const int t = threadIdx.x;
    const int blk = blockIdx.x;
    if (blk == 0) {
        // w1 packed [64][64]: cols <- ref cols 3..66 (g only; corr/offs/flow are f32 fixes)
        for (int i = t; i < 64 * 64; i += 256) {
            const int m = i >> 6, k = i & 63;
            wpk[W1OFS + i] = f2bf(w1[m * 69 + 3 + k]);
        }
    } else if (blk == 1) {
        for (int i = t; i < 64 * 64; i += 256) wpk[W2OFS + i] = f2bf(w2[i]);
    } else if (blk == 2) {
        for (int i = t; i < 64 * 64; i += 256) wpk[W3OFS + i] = f2bf(w3[i]);
    } else if (blk == 3) {
        for (int i = t; i < 64 * 128; i += 256) wpk[WFOFS + i] = f2bf(wf[i]);
    } else if (t < 64) {
        fws[t]       = b1[t];
        fws[64 + t]  = b2[t];
        fws[128 + t] = b3[t];
        fws[192 + t] = bf[t];
        fws[256 + t] = w1[t * 69 + 1];   // offset-x column (f32 path)
        fws[320 + t] = w1[t * 69 + 2];   // offset-y column
        fws[384 + t] = w1[t * 69 + 0];   // corr column
        fws[448 + t] = w1[t * 69 + 67];  // flow-x column
        fws[512 + t] = w1[t * 69 + 68];  // flow-y column
    }
}

// ---------------- prepass: point table [B][N] row = 64 bf16 g + pad + 4 f32 ----------------
__global__ __launch_bounds__(256) void prep_t(
    const float* __restrict__ xy, const float* __restrict__ f3d,
    const float* __restrict__ lf3d, char* __restrict__ pt)
{
    const int t = threadIdx.x;
    const int cq = t >> 6;                 // channel quarter 0..3
    const int l = t & 63;
    const int gn = blockIdx.x * 64 + l;
    const int b = blockIdx.y;
    half_u r;
#pragma unroll
    for (int i = 0; i < 16; i++)
        r.u[i] = f2bf(f3d[(size_t)(b * CH + cq * 16 + i) * NN + gn]);
    char* row = pt + ((size_t)b * NN + gn) * PT_ROW;
    uint4* rq = (uint4*)row;
    rq[2 * cq] = r.q[0];
    rq[2 * cq + 1] = r.q[1];
    if (cq == 0) {
        float4 e;
        e.x = xy[(size_t)(b * 2 + 0) * NN + gn];
        e.y = xy[(size_t)(b * 2 + 1) * NN + gn];
        e.z = lf3d[(size_t)(b * 2 + 0) * NN + gn];
        e.w = lf3d[(size_t)(b * 2 + 1) * NN + gn];
        *(float4*)(row + 144) = e;
    }
}

// ---------------- MFMA layer core (wave owns rows [32w, 32w+32), acc[4][2]) ----------------
template<int KT, int KROW, bool LO>
static __device__ __forceinline__ void layer_mfma(
    const unsigned short* __restrict__ wrow,
    const unsigned short* Xh, const unsigned short* Xl,
    int w, int ln, int q, f32x4 acc[4][2])
{
#pragma unroll
    for (int kt = 0; kt < KT; kt++) {
        const int kcol = kt * 32 + q * 8;
        short8 A[4];
#pragma unroll
        for (int mi = 0; mi < 4; mi++)
            A[mi] = *(const short8*)(wrow + (mi * 16 + ln) * KROW + kcol);
#pragma unroll
        for (int ni = 0; ni < 2; ni++) {
            const int nr = 32 * w + ni * 16 + ln;
            short8 bh = *(const short8*)(Xh + nr * XPITCH + kcol);
            short8 bl = bh;
            if (LO) bl = *(const short8*)(Xl + nr * LPITCH + kcol);
#pragma unroll
            for (int mi = 0; mi < 4; mi++) {
                acc[mi][ni] = __builtin_amdgcn_mfma_f32_16x16x32_bf16(A[mi], bh, acc[mi][ni], 0, 0, 0);
                if (LO)
                    acc[mi][ni] = __builtin_amdgcn_mfma_f32_16x16x32_bf16(A[mi], bl, acc[mi][ni], 0, 0, 0);
            }
        }
    }
}

static __device__ __forceinline__ void zero_acc(f32x4 acc[4][2]) {
#pragma unroll
    for (int mi = 0; mi < 4; mi++)
#pragma unroll
        for (int ni = 0; ni < 2; ni++)
#pragma unroll
            for (int r = 0; r < 4; r++) acc[mi][ni][r] = 0.f;
}

// epilogue: leaky(acc + bias [+ rank-5 f32 fix]) -> X hi/lo (wave-private rows)
static __device__ __forceinline__ void epi_x(
    f32x4 acc[4][2], const float* __restrict__ fws, int bofs, bool off_fix,
    const float* offsp, const float* auxp, unsigned short* Xh, unsigned short* Xl,
    int w, int ln, int q)
{
#pragma unroll
    for (int mi = 0; mi < 4; mi++) {
        const float4 bias = *(const float4*)(fws + bofs + mi * 16 + q * 4);
        float4 wox = bias, woy = bias, wco = bias, wfx = bias, wfy = bias;
        if (off_fix) {
            wox = *(const float4*)(fws + 256 + mi * 16 + q * 4);
            woy = *(const float4*)(fws + 320 + mi * 16 + q * 4);
            wco = *(const float4*)(fws + 384 + mi * 16 + q * 4);
            wfx = *(const float4*)(fws + 448 + mi * 16 + q * 4);
            wfy = *(const float4*)(fws + 512 + mi * 16 + q * 4);
        }
#pragma unroll
        for (int ni = 0; ni < 2; ni++) {
            const int nr = 32 * w + ni * 16 + ln;
            float ox = 0.f, oy = 0.f, co = 0.f, fx = 0.f, fy = 0.f;
            if (off_fix) {
                ox = offsp[nr]; oy = offsp[NT + nr];
                co = auxp[nr];  fx = auxp[NT + nr]; fy = auxp[2 * NT + nr];
            }
            unsigned int hh0 = 0, hh1 = 0, ll0 = 0, ll1 = 0;
#pragma unroll
            for (int r = 0; r < 4; r++) {
                float a = acc[mi][ni][r] + ((const float*)&bias)[r];
                if (off_fix) {
                    a += ((const float*)&wox)[r] * ox + ((const float*)&woy)[r] * oy;
                    a += ((const float*)&wco)[r] * co;
                    a += ((const float*)&wfx)[r] * fx + ((const float*)&wfy)[r] * fy;
                }
                a = fmaxf(a, 0.1f * a);
                const unsigned short hb = f2bf(a);
                const unsigned short lb = f2bf(a - bf2f(hb));
                if (r == 0) { hh0 = hb; ll0 = lb; }
                if (r == 1) { hh0 |= ((unsigned)hb) << 16; ll0 |= ((unsigned)lb) << 16; }
                if (r == 2) { hh1 = hb; ll1 = lb; }
                if (r == 3) { hh1 |= ((unsigned)hb) << 16; ll1 |= ((unsigned)lb) << 16; }
            }
            *(uint2*)&Xh[nr * XPITCH + mi * 16 + q * 4] = make_uint2(hh0, hh1);
            *(uint2*)&Xl[nr * LPITCH + mi * 16 + q * 4] = make_uint2(ll0, ll1);
        }
    }
}

// ---------------- main fused kernel: 256 thr, zero barriers, 4 blocks/CU ----------------
// LDS = 39,424 B -> 4 blocks/CU = 16 waves/CU = 4 waves/SIMD. All LDS traffic wave-private.
__global__ __launch_bounds__(256, 4) void fuse(
    const float* __restrict__ feat2d, const float* __restrict__ lf2d,
    const int* __restrict__ nn,
    const unsigned short* __restrict__ wpk, const float* __restrict__ fws,
    const char* __restrict__ ptab,
    float* __restrict__ out)
{
    __shared__ unsigned short Xhi[NT * XPITCH];   // 18432 B, K cols 0..63 (+pad)
    __shared__ unsigned short Xlo[NT * LPITCH];   // 18432 B
    __shared__ float offsS[2 * NT];               //  1024 B
    __shared__ float auxS[3 * NT];                //  1536 B (corr, fcx, fcy)

    const int tid = threadIdx.x;
    const int w = tid >> 6, lane = tid & 63;
    const int q = lane >> 4, ln = lane & 15;
    const int b = blockIdx.y;
    const int p0 = blockIdx.x * NT;

    { // stage 0 (wave-private): lane = (cp = channel half, j = pixel-in-wave)
        const int cp = lane >> 5, j = lane & 31;
        const int n = 32 * w + j;
        const int p = p0 + n;
        const int idx = nn[(size_t)b * HW + p];
        const char* prow = ptab + ((size_t)b * NN + idx) * PT_ROW;
        row_u g;
#pragma unroll
        for (int k = 0; k < 4; k++) g.q[k] = ((const uint4*)prow)[cp * 4 + k];
        float ca = 0.f;
#pragma unroll
        for (int i = 0; i < 32; i++) {
            const int c = cp * 32 + i;
            ca += feat2d[(size_t)(b * CH + c) * HW + p] * bf2f(g.u[i]);
        }
        uint4* xp = (uint4*)&Xhi[n * XPITCH + cp * 32];
#pragma unroll
        for (int k = 0; k < 4; k++) xp[k] = g.q[k];
        ca += __shfl_xor(ca, 32);        // combine the two channel-halves in-wave
        if (cp == 0) {
            const float4 e = *(const float4*)(prow + 144);
            offsS[n] = e.x - (float)(p & 255);
            offsS[NT + n] = e.y - (float)(p >> 8);
            auxS[n] = ca * (1.0f / 64.0f);                              // corr (f32 path)
            auxS[NT + n] = e.z - lf2d[(size_t)(b * 2 + 0) * HW + p];    // fcx
            auxS[2 * NT + n] = e.w - lf2d[(size_t)(b * 2 + 1) * HW + p];// fcy
        }
    }
    // no __syncthreads: all LDS deps are intra-wave (ordered via lgkmcnt)

    f32x4 acc[4][2];
    // L1 (K=64, g only, X hi; corr/offset/flow enter via rank-5 f32 fix)
    zero_acc(acc);
    layer_mfma<2, 64, false>(wpk + W1OFS, Xhi, Xlo, w, ln, q, acc);
    epi_x(acc, fws, 0, true, offsS, auxS, Xhi, Xlo, w, ln, q);
    // L2
    zero_acc(acc);
    layer_mfma<2, 64, true>(wpk + W2OFS, Xhi, Xlo, w, ln, q, acc);
    epi_x(acc, fws, 64, false, offsS, auxS, Xhi, Xlo, w, ln, q);
    // L3
    zero_acc(acc);
    layer_mfma<2, 64, true>(wpk + W3OFS, Xhi, Xlo, w, ln, q, acc);
    epi_x(acc, fws, 128, false, offsS, auxS, Xhi, Xlo, w, ln, q);
    // Lf: k 0-63 = x3 (LDS, hi+lo), k 64-127 = feat2d (global, L2-hot, hi only)
    zero_acc(acc);
    layer_mfma<2, 128, true>(wpk + WFOFS, Xhi, Xlo, w, ln, q, acc);
#pragma unroll
    for (int kt = 2; kt < 4; kt++) {
        const int kcol = kt * 32 + q * 8;
        short8 A[4];
#pragma unroll
        for (int mi = 0; mi < 4; mi++)
            A[mi] = *(const short8*)(wpk + WFOFS + (mi * 16 + ln) * 128 + kcol);
#pragma unroll
        for (int ni = 0; ni < 2; ni++) {
            frag_u fh;
#pragma unroll
            for (int j = 0; j < 8; j++) {
                const int c = (kt - 2) * 32 + q * 8 + j;
                const float v = feat2d[(size_t)(b * CH + c) * HW + p0 + 32 * w + ni * 16 + ln];
                fh.u[j] = f2bf(v);
            }
#pragma unroll
            for (int mi = 0; mi < 4; mi++)
                acc[mi][ni] = __builtin_amdgcn_mfma_f32_16x16x32_bf16(A[mi], fh.v, acc[mi][ni], 0, 0, 0);
        }
    }
    // final epilogue -> out f32
#pragma unroll
    for (int mi = 0; mi < 4; mi++) {
        const float4 bias = *(const float4*)(fws + 192 + mi * 16 + q * 4);
#pragma unroll
        for (int ni = 0; ni < 2; ni++) {
#pragma unroll
            for (int r = 0; r < 4; r++) {
                float a = acc[mi][ni][r] + ((const float*)&bias)[r];
                a = fmaxf(a, 0.1f * a);
                const int m = mi * 16 + q * 4 + r;
                out[(size_t)(b * CH + m) * HW + p0 + 32 * w + ni * 16 + ln] = a;
            }
        }
    }
}

// ---------------- fallback (R4, passed): used only if ws too small ----------------
__global__ __launch_bounds__(256) void fuse_slow(
    const float* __restrict__ feat2d, const float* __restrict__ lf2d,
    const float* __restrict__ xy, const float* __restrict__ feat3d,
    const float* __restrict__ lf3d, const int* __restrict__ nn,
    const float* __restrict__ w1, const float* __restrict__ b1,
    const float* __restrict__ w2, const float* __restrict__ b2,
    const float* __restrict__ w3, const float* __restrict__ b3,
    const float* __restrict__ wf, const float* __restrict__ bfv,
    float* __restrict__ out)
{
    const int p = blockIdx.x * 256 + threadIdx.x;
    const int b = blockIdx.y;
    const int idx = nn[(size_t)b * HW + p];
    const float* f3 = feat3d + (size_t)b * CH * NN + idx;
    float g[CH];
#pragma unroll
    for (int c = 0; c < CH; c++) g[c] = f3[(size_t)c * NN];
    const float fl3x = lf3d[(size_t)(b * 2 + 0) * NN + idx];
    const float fl3y = lf3d[(size_t)(b * 2 + 1) * NN + idx];
    const float xyx = xy[(size_t)(b * 2 + 0) * NN + idx];
    const float xyy = xy[(size_t)(b * 2 + 1) * NN + idx];
    const float* f2p = feat2d + (size_t)b * CH * HW + p;
    float corr = 0.f;
#pragma unroll
    for (int c = 0; c < CH; c++) corr += f2p[(size_t)c * HW] * g[c];
    corr *= (1.f / 64.f);
    float xin[69];
    xin[0] = corr;
    xin[1] = xyx - (float)(p & 255);
    xin[2] = xyy - (float)(p >> 8);
#pragma unroll
    for (int c = 0; c < CH; c++) xin[3 + c] = g[c];
    xin[67] = fl3x - lf2d[(size_t)(b * 2 + 0) * HW + p];
    xin[68] = fl3y - lf2d[(size_t)(b * 2 + 1) * HW + p];
    float x1[64], x2[64], x3[64], accv[64];
#pragma unroll
    for (int o = 0; o < 64; o++) {
        float a = b1[o];
#pragma unroll
        for (int k = 0; k < 69; k++) a += w1[o * 69 + k] * xin[k];
        x1[o] = (a >= 0.f) ? a : 0.1f * a;
    }
#pragma unroll
    for (int o = 0; o < 64; o++) {
        float a = b2[o];
#pragma unroll
        for (int k = 0; k < 64; k++) a += w2[o * 64 + k] * x1[k];
        x2[o] = (a >= 0.f) ? a : 0.1f * a;
    }
#pragma unroll
    for (int o = 0; o < 64; o++) {
        float a = b3[o];
#pragma unroll
        for (int k = 0; k < 64; k++) a += w3[o * 64 + k] * x2[k];
        x3[o] = (a >= 0.f) ? a : 0.1f * a;
    }
#pragma unroll
    for (int o = 0; o < 64; o++) {
        float a = bfv[o];
#pragma unroll
        for (int k = 0; k < 64; k++) a += wf[o * 128 + k] * x3[k];
        accv[o] = a;
    }
#pragma unroll
    for (int k = 0; k < 64; k++) {
        const float f = f2p[(size_t)k * HW];
#pragma unroll
        for (int o = 0; o < 64; o++) accv[o] += wf[o * 128 + 64 + k] * f;
    }
#pragma unroll
    for (int o = 0; o < 64; o++) {
        float a = accv[o];
        a = (a >= 0.f) ? a : 0.1f * a;
        out[(size_t)(b * CH + o) * HW + p] = a;
    }
}

extern "C" void kernel_launch(void* const* d_in, const int* in_sizes, int n_in,
                              void* d_out, int out_size, void* d_ws, size_t ws_size,
                              hipStream_t stream)
{
    const float* xy   = (const float*)d_in[0];
    const float* f2d  = (const float*)d_in[1];
    const float* f3d  = (const float*)d_in[2];
    const float* lf2d = (const float*)d_in[3];
    const float* lf3d = (const float*)d_in[4];
    const int*   nn   = (const int*)d_in[5];
    const float* w1 = (const float*)d_in[6];
    const float* b1 = (const float*)d_in[7];
    const float* w2 = (const float*)d_in[8];
    const float* b2 = (const float*)d_in[9];
    const float* w3 = (const float*)d_in[10];
    const float* b3 = (const float*)d_in[11];
    const float* wf = (const float*)d_in[12];
    const float* bf = (const float*)d_in[13];

    if (ws_size >= WS_NEED) {
        unsigned short* wpk = (unsigned short*)d_ws;
        float* fws = (float*)((char*)d_ws + FWS_BYTE);
        char* pt = (char*)d_ws + PTAB_BYTE;
        prep_w<<<dim3(5), 256, 0, stream>>>(w1, b1, w2, b2, w3, b3, wf, bf, wpk, fws);
        prep_t<<<dim3(NN / 64, BB), 256, 0, stream>>>(xy, f3d, lf3d, pt);
        fuse<<<dim3(HW / NT, BB), 256, 0, stream>>>(f2d, lf2d, nn, wpk, fws, pt, (float*)d_out);
    } else {
        fuse_slow<<<dim3(HW / 256, BB), 256, 0, stream>>>(f2d, lf2d, xy, f3d, lf3d, nn,
                                                          w1, b1, w2, b2, w3, b3, wf, bf,
                                                          (float*)d_out);
    }
}

// Round 5
// 219.913 us; speedup vs baseline: 1.2060x; 1.0328x over previous
//
#include <hip/hip_runtime.h>

#define BB 4
#define CH 64
#define HW 65536
#define NN 16384
#define NT 128
#define XPITCH 72
#define LPITCH 72
#define F2PITCH 72
#define W1OFS 0
#define W2OFS 4096
#define W3OFS 8192
#define WFOFS 12288
#define FWS_BYTE 46080
#define PTAB_BYTE 49152
#define PT_ROW 160
#define WS_NEED ((size_t)PTAB_BYTE + (size_t)BB * NN * PT_ROW)

typedef __attribute__((ext_vector_type(8))) short short8;
typedef __attribute__((ext_vector_type(4))) float f32x4;

union frag_u { unsigned short u[8]; short8 v; };
union row_u  { uint4 q[4]; unsigned short u[32]; };
union half_u { uint4 q[2]; unsigned short u[16]; };

static __device__ __forceinline__ unsigned short f2bf(float x) {
    unsigned int u = __float_as_uint(x);
    return (unsigned short)((u + 0x7fffu + ((u >> 16) & 1u)) >> 16);
}
static __device__ __forceinline__ float bf2f(unsigned short h) {
    return __uint_as_float(((unsigned int)h) << 16);
}

// ---------------- merged prepass: weights (blocks >= NN/64) + point table ----------------
// fws layout (f32): 0 b1 | 64 b2 | 128 b3 | 192 bf | 256 w_ox | 320 w_oy |
//                   384 w_corr | 448 w_fx | 512 w_fy
__global__ __launch_bounds__(256) void prep(
    const float* __restrict__ xy, const float* __restrict__ f3d,
    const float* __restrict__ lf3d,
    const float* __restrict__ w1, const float* __restrict__ b1,
    const float* __restrict__ w2, const float* __restrict__ b2,
    const float* __restrict__ w3, const float* __restrict__ b3,
    const float* __restrict__ wf, const float* __restrict__ bf,
    unsigned short* __restrict__ wpk, float* __restrict__ fws,
    char* __restrict__ pt)
{
    const int t = threadIdx.x;
    const int bx = blockIdx.x;
    if (bx >= NN / 64) {
        if (blockIdx.y != 0) return;
        const int blk = bx - NN / 64;
        if (blk == 0) {
            // w1 packed [64][64]: cols <- ref cols 3..66 (g only; corr/offs/flow are f32 fixes)
            for (int i = t; i < 64 * 64; i += 256) {
                const int m = i >> 6, k = i & 63;
                wpk[W1OFS + i] = f2bf(w1[m * 69 + 3 + k]);
            }
        } else if (blk == 1) {
            for (int i = t; i < 64 * 64; i += 256) wpk[W2OFS + i] = f2bf(w2[i]);
        } else if (blk == 2) {
            for (int i = t; i < 64 * 64; i += 256) wpk[W3OFS + i] = f2bf(w3[i]);
        } else if (blk == 3) {
            for (int i = t; i < 64 * 128; i += 256) wpk[WFOFS + i] = f2bf(wf[i]);
        } else if (t < 64) {
            fws[t]       = b1[t];
            fws[64 + t]  = b2[t];
            fws[128 + t] = b3[t];
            fws[192 + t] = bf[t];
            fws[256 + t] = w1[t * 69 + 1];   // offset-x column (f32 path)
            fws[320 + t] = w1[t * 69 + 2];   // offset-y column
            fws[384 + t] = w1[t * 69 + 0];   // corr column
            fws[448 + t] = w1[t * 69 + 67];  // flow-x column
            fws[512 + t] = w1[t * 69 + 68];  // flow-y column
        }
        return;
    }
    // point table: [B][N] row = 64 bf16 g + pad + 4 f32
    const int cq = t >> 6;                 // channel quarter 0..3
    const int l = t & 63;
    const int gn = bx * 64 + l;
    const int b = blockIdx.y;
    half_u r;
#pragma unroll
    for (int i = 0; i < 16; i++)
        r.u[i] = f2bf(f3d[(size_t)(b * CH + cq * 16 + i) * NN + gn]);
    char* row = pt + ((size_t)b * NN + gn) * PT_ROW;
    uint4* rq = (uint4*)row;
    rq[2 * cq] = r.q[0];
    rq[2 * cq + 1] = r.q[1];
    if (cq == 0) {
        float4 e;
        e.x = xy[(size_t)(b * 2 + 0) * NN + gn];
        e.y = xy[(size_t)(b * 2 + 1) * NN + gn];
        e.z = lf3d[(size_t)(b * 2 + 0) * NN + gn];
        e.w = lf3d[(size_t)(b * 2 + 1) * NN + gn];
        *(float4*)(row + 144) = e;
    }
}

// ---------------- MFMA layer core (wave owns rows [32w, 32w+32), acc[4][2]) ----------------
template<int KT, int KROW, bool LO>
static __device__ __forceinline__ void layer_mfma(
    const unsigned short* __restrict__ wrow,
    const unsigned short* Xh, const unsigned short* Xl,
    int w, int ln, int q, f32x4 acc[4][2])
{
#pragma unroll
    for (int kt = 0; kt < KT; kt++) {
        const int kcol = kt * 32 + q * 8;
        short8 A[4];
#pragma unroll
        for (int mi = 0; mi < 4; mi++)
            A[mi] = *(const short8*)(wrow + (mi * 16 + ln) * KROW + kcol);
#pragma unroll
        for (int ni = 0; ni < 2; ni++) {
            const int nr = 32 * w + ni * 16 + ln;
            short8 bh = *(const short8*)(Xh + nr * XPITCH + kcol);
            short8 bl = bh;
            if (LO) bl = *(const short8*)(Xl + nr * LPITCH + kcol);
#pragma unroll
            for (int mi = 0; mi < 4; mi++) {
                acc[mi][ni] = __builtin_amdgcn_mfma_f32_16x16x32_bf16(A[mi], bh, acc[mi][ni], 0, 0, 0);
                if (LO)
                    acc[mi][ni] = __builtin_amdgcn_mfma_f32_16x16x32_bf16(A[mi], bl, acc[mi][ni], 0, 0, 0);
            }
        }
    }
}

static __device__ __forceinline__ void zero_acc(f32x4 acc[4][2]) {
#pragma unroll
    for (int mi = 0; mi < 4; mi++)
#pragma unroll
        for (int ni = 0; ni < 2; ni++)
#pragma unroll
            for (int r = 0; r < 4; r++) acc[mi][ni][r] = 0.f;
}

// epilogue: leaky(acc + bias [+ rank-5 f32 fix]) -> X hi/lo (wave-private rows)
static __device__ __forceinline__ void epi_x(
    f32x4 acc[4][2], const float* __restrict__ fws, int bofs, bool off_fix,
    const float* offsp, const float* auxp, unsigned short* Xh, unsigned short* Xl,
    int w, int ln, int q)
{
#pragma unroll
    for (int mi = 0; mi < 4; mi++) {
        const float4 bias = *(const float4*)(fws + bofs + mi * 16 + q * 4);
        float4 wox = bias, woy = bias, wco = bias, wfx = bias, wfy = bias;
        if (off_fix) {
            wox = *(const float4*)(fws + 256 + mi * 16 + q * 4);
            woy = *(const float4*)(fws + 320 + mi * 16 + q * 4);
            wco = *(const float4*)(fws + 384 + mi * 16 + q * 4);
            wfx = *(const float4*)(fws + 448 + mi * 16 + q * 4);
            wfy = *(const float4*)(fws + 512 + mi * 16 + q * 4);
        }
#pragma unroll
        for (int ni = 0; ni < 2; ni++) {
            const int nr = 32 * w + ni * 16 + ln;
            float ox = 0.f, oy = 0.f, co = 0.f, fx = 0.f, fy = 0.f;
            if (off_fix) {
                ox = offsp[nr]; oy = offsp[NT + nr];
                co = auxp[nr];  fx = auxp[NT + nr]; fy = auxp[2 * NT + nr];
            }
            unsigned int hh0 = 0, hh1 = 0, ll0 = 0, ll1 = 0;
#pragma unroll
            for (int r = 0; r < 4; r++) {
                float a = acc[mi][ni][r] + ((const float*)&bias)[r];
                if (off_fix) {
                    a += ((const float*)&wox)[r] * ox + ((const float*)&woy)[r] * oy;
                    a += ((const float*)&wco)[r] * co;
                    a += ((const float*)&wfx)[r] * fx + ((const float*)&wfy)[r] * fy;
                }
                a = fmaxf(a, 0.1f * a);
                const unsigned short hb = f2bf(a);
                const unsigned short lb = f2bf(a - bf2f(hb));
                if (r == 0) { hh0 = hb; ll0 = lb; }
                if (r == 1) { hh0 |= ((unsigned)hb) << 16; ll0 |= ((unsigned)lb) << 16; }
                if (r == 2) { hh1 = hb; ll1 = lb; }
                if (r == 3) { hh1 |= ((unsigned)hb) << 16; ll1 |= ((unsigned)lb) << 16; }
            }
            *(uint2*)&Xh[nr * XPITCH + mi * 16 + q * 4] = make_uint2(hh0, hh1);
            *(uint2*)&Xl[nr * LPITCH + mi * 16 + q * 4] = make_uint2(ll0, ll1);
        }
    }
}

// ---------------- main fused kernel: 256 thr, zero barriers, vectorized staging ----------------
// LDS = 57,856 B -> 2 blocks/CU. Per wave: 8x float4 feat2d loads (vs 32 scalar),
// feat2d tile staged once in F2 (bf16) and reused by corr + Lf (no 2nd global pass).
__global__ __launch_bounds__(256, 2) void fuse(
    const float* __restrict__ feat2d, const float* __restrict__ lf2d,
    const int* __restrict__ nn,
    const unsigned short* __restrict__ wpk, const float* __restrict__ fws,
    const char* __restrict__ ptab,
    float* __restrict__ out)
{
    __shared__ unsigned short Xhi[NT * XPITCH];   // 18432 B, K cols 0..63 (+pad)
    __shared__ unsigned short Xlo[NT * LPITCH];   // 18432 B
    __shared__ unsigned short F2[NT * F2PITCH];   // 18432 B, feat2d tile bf16 [px][ch]
    __shared__ float offsS[2 * NT];               //  1024 B
    __shared__ float auxS[3 * NT];                //  1536 B (corr, fcx, fcy)

    const int tid = threadIdx.x;
    const int w = tid >> 6, lane = tid & 63;
    const int q = lane >> 4, ln = lane & 15;
    const int b = blockIdx.y;
    const int p0 = blockIdx.x * NT;

    { // phase A (wave-private): vectorized feat2d tile -> F2 bf16
        const int ci = lane >> 3;        // channel group (8 ch each)
        const int qd = lane & 7;         // pixel quad (4 px each)
        const int px0 = 32 * w + qd * 4;
        float4 fv[8];
#pragma unroll
        for (int cc = 0; cc < 8; cc++) {
            const int c = ci * 8 + cc;
            fv[cc] = *(const float4*)(feat2d + (size_t)(b * CH + c) * HW + p0 + px0);
        }
#pragma unroll
        for (int px = 0; px < 4; px++) {
            frag_u fr;
#pragma unroll
            for (int cc = 0; cc < 8; cc++)
                fr.u[cc] = f2bf(((const float*)&fv[cc])[px]);
            *(short8*)&F2[(px0 + px) * F2PITCH + ci * 8] = fr.v;
        }
    }

    { // phase B (wave-private): gather g, corr from F2, aux terms
        const int cp = lane >> 5, j = lane & 31;
        const int n = 32 * w + j;
        const int p = p0 + n;
        const int idx = nn[(size_t)b * HW + p];
        const char* prow = ptab + ((size_t)b * NN + idx) * PT_ROW;
        row_u g;
#pragma unroll
        for (int k = 0; k < 4; k++) g.q[k] = ((const uint4*)prow)[cp * 4 + k];
        uint4* xp = (uint4*)&Xhi[n * XPITCH + cp * 32];
#pragma unroll
        for (int k = 0; k < 4; k++) xp[k] = g.q[k];
        // corr: f2 (bf16, LDS) dot g (bf16, regs), f32 accumulate
        frag_u f2v[4];
#pragma unroll
        for (int k = 0; k < 4; k++)
            f2v[k].v = *(const short8*)&F2[n * F2PITCH + cp * 32 + k * 8];
        float ca = 0.f;
#pragma unroll
        for (int i = 0; i < 32; i++)
            ca += bf2f(f2v[i >> 3].u[i & 7]) * bf2f(g.u[i]);
        ca += __shfl_xor(ca, 32);        // combine the two channel-halves in-wave
        if (cp == 0) {
            const float4 e = *(const float4*)(prow + 144);
            offsS[n] = e.x - (float)(p & 255);
            offsS[NT + n] = e.y - (float)(p >> 8);
            auxS[n] = ca * (1.0f / 64.0f);                              // corr (f32 path)
            auxS[NT + n] = e.z - lf2d[(size_t)(b * 2 + 0) * HW + p];    // fcx
            auxS[2 * NT + n] = e.w - lf2d[(size_t)(b * 2 + 1) * HW + p];// fcy
        }
    }
    // no __syncthreads: all LDS deps are intra-wave (ordered via lgkmcnt)

    f32x4 acc[4][2];
    // L1 (K=64, g only, X hi; corr/offset/flow enter via rank-5 f32 fix)
    zero_acc(acc);
    layer_mfma<2, 64, false>(wpk + W1OFS, Xhi, Xlo, w, ln, q, acc);
    epi_x(acc, fws, 0, true, offsS, auxS, Xhi, Xlo, w, ln, q);
    // L2
    zero_acc(acc);
    layer_mfma<2, 64, true>(wpk + W2OFS, Xhi, Xlo, w, ln, q, acc);
    epi_x(acc, fws, 64, false, offsS, auxS, Xhi, Xlo, w, ln, q);
    // L3
    zero_acc(acc);
    layer_mfma<2, 64, true>(wpk + W3OFS, Xhi, Xlo, w, ln, q, acc);
    epi_x(acc, fws, 128, false, offsS, auxS, Xhi, Xlo, w, ln, q);
    // Lf: k 0-63 = x3 (LDS, hi+lo), k 64-127 = feat2d tile (F2 LDS, hi only)
    zero_acc(acc);
    layer_mfma<2, 128, true>(wpk + WFOFS, Xhi, Xlo, w, ln, q, acc);
#pragma unroll
    for (int kt = 2; kt < 4; kt++) {
        const int kcol = kt * 32 + q * 8;
        short8 A[4];
#pragma unroll
        for (int mi = 0; mi < 4; mi++)
            A[mi] = *(const short8*)(wpk + WFOFS + (mi * 16 + ln) * 128 + kcol);
#pragma unroll
        for (int ni = 0; ni < 2; ni++) {
            const int nr = 32 * w + ni * 16 + ln;
            frag_u fh;
            fh.v = *(const short8*)&F2[nr * F2PITCH + (kt - 2) * 32 + q * 8];
#pragma unroll
            for (int mi = 0; mi < 4; mi++)
                acc[mi][ni] = __builtin_amdgcn_mfma_f32_16x16x32_bf16(A[mi], fh.v, acc[mi][ni], 0, 0, 0);
        }
    }
    // final epilogue -> out f32
#pragma unroll
    for (int mi = 0; mi < 4; mi++) {
        const float4 bias = *(const float4*)(fws + 192 + mi * 16 + q * 4);
#pragma unroll
        for (int ni = 0; ni < 2; ni++) {
#pragma unroll
            for (int r = 0; r < 4; r++) {
                float a = acc[mi][ni][r] + ((const float*)&bias)[r];
                a = fmaxf(a, 0.1f * a);
                const int m = mi * 16 + q * 4 + r;
                out[(size_t)(b * CH + m) * HW + p0 + 32 * w + ni * 16 + ln] = a;
            }
        }
    }
}

// ---------------- fallback (R4, passed): used only if ws too small ----------------
__global__ __launch_bounds__(256) void fuse_slow(
    const float* __restrict__ feat2d, const float* __restrict__ lf2d,
    const float* __restrict__ xy, const float* __restrict__ feat3d,
    const float* __restrict__ lf3d, const int* __restrict__ nn,
    const float* __restrict__ w1, const float* __restrict__ b1,
    const float* __restrict__ w2, const float* __restrict__ b2,
    const float* __restrict__ w3, const float* __restrict__ b3,
    const float* __restrict__ wf, const float* __restrict__ bfv,
    float* __restrict__ out)
{
    const int p = blockIdx.x * 256 + threadIdx.x;
    const int b = blockIdx.y;
    const int idx = nn[(size_t)b * HW + p];
    const float* f3 = feat3d + (size_t)b * CH * NN + idx;
    float g[CH];
#pragma unroll
    for (int c = 0; c < CH; c++) g[c] = f3[(size_t)c * NN];
    const float fl3x = lf3d[(size_t)(b * 2 + 0) * NN + idx];
    const float fl3y = lf3d[(size_t)(b * 2 + 1) * NN + idx];
    const float xyx = xy[(size_t)(b * 2 + 0) * NN + idx];
    const float xyy = xy[(size_t)(b * 2 + 1) * NN + idx];
    const float* f2p = feat2d + (size_t)b * CH * HW + p;
    float corr = 0.f;
#pragma unroll
    for (int c = 0; c < CH; c++) corr += f2p[(size_t)c * HW] * g[c];
    corr *= (1.f / 64.f);
    float xin[69];
    xin[0] = corr;
    xin[1] = xyx - (float)(p & 255);
    xin[2] = xyy - (float)(p >> 8);
#pragma unroll
    for (int c = 0; c < CH; c++) xin[3 + c] = g[c];
    xin[67] = fl3x - lf2d[(size_t)(b * 2 + 0) * HW + p];
    xin[68] = fl3y - lf2d[(size_t)(b * 2 + 1) * HW + p];
    float x1[64], x2[64], x3[64], accv[64];
#pragma unroll
    for (int o = 0; o < 64; o++) {
        float a = b1[o];
#pragma unroll
        for (int k = 0; k < 69; k++) a += w1[o * 69 + k] * xin[k];
        x1[o] = (a >= 0.f) ? a : 0.1f * a;
    }
#pragma unroll
    for (int o = 0; o < 64; o++) {
        float a = b2[o];
#pragma unroll
        for (int k = 0; k < 64; k++) a += w2[o * 64 + k] * x1[k];
        x2[o] = (a >= 0.f) ? a : 0.1f * a;
    }
#pragma unroll
    for (int o = 0; o < 64; o++) {
        float a = b3[o];
#pragma unroll
        for (int k = 0; k < 64; k++) a += w3[o * 64 + k] * x2[k];
        x3[o] = (a >= 0.f) ? a : 0.1f * a;
    }
#pragma unroll
    for (int o = 0; o < 64; o++) {
        float a = bfv[o];
#pragma unroll
        for (int k = 0; k < 64; k++) a += wf[o * 128 + k] * x3[k];
        accv[o] = a;
    }
#pragma unroll
    for (int k = 0; k < 64; k++) {
        const float f = f2p[(size_t)k * HW];
#pragma unroll
        for (int o = 0; o < 64; o++) accv[o] += wf[o * 128 + 64 + k] * f;
    }
#pragma unroll
    for (int o = 0; o < 64; o++) {
        float a = accv[o];
        a = (a >= 0.f) ? a : 0.1f * a;
        out[(size_t)(b * CH + o) * HW + p] = a;
    }
}

extern "C" void kernel_launch(void* const* d_in, const int* in_sizes, int n_in,
                              void* d_out, int out_size, void* d_ws, size_t ws_size,
                              hipStream_t stream)
{
    const float* xy   = (const float*)d_in[0];
    const float* f2d  = (const float*)d_in[1];
    const float* f3d  = (const float*)d_in[2];
    const float* lf2d = (const float*)d_in[3];
    const float* lf3d = (const float*)d_in[4];
    const int*   nn   = (const int*)d_in[5];
    const float* w1 = (const float*)d_in[6];
    const float* b1 = (const float*)d_in[7];
    const float* w2 = (const float*)d_in[8];
    const float* b2 = (const float*)d_in[9];
    const float* w3 = (const float*)d_in[10];
    const float* b3 = (const float*)d_in[11];
    const float* wf = (const float*)d_in[12];
    const float* bf = (const float*)d_in[13];

    if (ws_size >= WS_NEED) {
        unsigned short* wpk = (unsigned short*)d_ws;
        float* fws = (float*)((char*)d_ws + FWS_BYTE);
        char* pt = (char*)d_ws + PTAB_BYTE;
        prep<<<dim3(NN / 64 + 5, BB), 256, 0, stream>>>(xy, f3d, lf3d,
                                                        w1, b1, w2, b2, w3, b3, wf, bf,
                                                        wpk, fws, pt);
        fuse<<<dim3(HW / NT, BB), 256, 0, stream>>>(f2d, lf2d, nn, wpk, fws, pt, (float*)d_out);
    } else {
        fuse_slow<<<dim3(HW / 256, BB), 256, 0, stream>>>(f2d, lf2d, xy, f3d, lf3d, nn,
                                                          w1, b1, w2, b2, w3, b3, wf, bf,
                                                          (float*)d_out);
    }
}

// Round 6
// 216.769 us; speedup vs baseline: 1.2235x; 1.0145x over previous
//
#include <hip/hip_runtime.h>

#define BB 4
#define CH 64
#define HW 65536
#define NN 16384
#define NT 128
#define TW 256
#define XPITCH 72
#define LPITCH 72
#define F2PITCH 72
#define W1OFS 0
#define W2OFS 4096
#define W3OFS 8192
#define WFOFS 12288
#define FWS_BYTE 46080
#define PTAB_BYTE 49152
#define PT_ROW 160
#define WS_NEED ((size_t)PTAB_BYTE + (size_t)BB * NN * PT_ROW)

typedef __attribute__((ext_vector_type(8))) short short8;
typedef __attribute__((ext_vector_type(4))) float f32x4;

union frag_u { unsigned short u[8]; short8 v; };
union row_u  { uint4 q[4]; unsigned short u[32]; };
union half_u { uint4 q[2]; unsigned short u[16]; };

static __device__ __forceinline__ unsigned short f2bf(float x) {
    unsigned int u = __float_as_uint(x);
    return (unsigned short)((u + 0x7fffu + ((u >> 16) & 1u)) >> 16);
}
static __device__ __forceinline__ float bf2f(unsigned short h) {
    return __uint_as_float(((unsigned int)h) << 16);
}

// ---------------- merged prepass: weights (blocks >= NN/64) + point table ----------------
// fws layout (f32): 0 b1 | 64 b2 | 128 b3 | 192 bf | 256 w_ox | 320 w_oy |
//                   384 w_corr | 448 w_fx | 512 w_fy
__global__ __launch_bounds__(256) void prep(
    const float* __restrict__ xy, const float* __restrict__ f3d,
    const float* __restrict__ lf3d,
    const float* __restrict__ w1, const float* __restrict__ b1,
    const float* __restrict__ w2, const float* __restrict__ b2,
    const float* __restrict__ w3, const float* __restrict__ b3,
    const float* __restrict__ wf, const float* __restrict__ bf,
    unsigned short* __restrict__ wpk, float* __restrict__ fws,
    char* __restrict__ pt)
{
    const int t = threadIdx.x;
    const int bx = blockIdx.x;
    if (bx >= NN / 64) {
        if (blockIdx.y != 0) return;
        const int blk = bx - NN / 64;
        if (blk == 0) {
            // w1 packed [64][64]: cols <- ref cols 3..66 (g only; corr/offs/flow are f32 fixes)
            for (int i = t; i < 64 * 64; i += 256) {
                const int m = i >> 6, k = i & 63;
                wpk[W1OFS + i] = f2bf(w1[m * 69 + 3 + k]);
            }
        } else if (blk == 1) {
            for (int i = t; i < 64 * 64; i += 256) wpk[W2OFS + i] = f2bf(w2[i]);
        } else if (blk == 2) {
            for (int i = t; i < 64 * 64; i += 256) wpk[W3OFS + i] = f2bf(w3[i]);
        } else if (blk == 3) {
            for (int i = t; i < 64 * 128; i += 256) wpk[WFOFS + i] = f2bf(wf[i]);
        } else if (t < 64) {
            fws[t]       = b1[t];
            fws[64 + t]  = b2[t];
            fws[128 + t] = b3[t];
            fws[192 + t] = bf[t];
            fws[256 + t] = w1[t * 69 + 1];   // offset-x column (f32 path)
            fws[320 + t] = w1[t * 69 + 2];   // offset-y column
            fws[384 + t] = w1[t * 69 + 0];   // corr column
            fws[448 + t] = w1[t * 69 + 67];  // flow-x column
            fws[512 + t] = w1[t * 69 + 68];  // flow-y column
        }
        return;
    }
    // point table: [B][N] row = 64 bf16 g + pad + 4 f32
    const int cq = t >> 6;                 // channel quarter 0..3
    const int l = t & 63;
    const int gn = bx * 64 + l;
    const int b = blockIdx.y;
    half_u r;
#pragma unroll
    for (int i = 0; i < 16; i++)
        r.u[i] = f2bf(f3d[(size_t)(b * CH + cq * 16 + i) * NN + gn]);
    char* row = pt + ((size_t)b * NN + gn) * PT_ROW;
    uint4* rq = (uint4*)row;
    rq[2 * cq] = r.q[0];
    rq[2 * cq + 1] = r.q[1];
    if (cq == 0) {
        float4 e;
        e.x = xy[(size_t)(b * 2 + 0) * NN + gn];
        e.y = xy[(size_t)(b * 2 + 1) * NN + gn];
        e.z = lf3d[(size_t)(b * 2 + 0) * NN + gn];
        e.w = lf3d[(size_t)(b * 2 + 1) * NN + gn];
        *(float4*)(row + 144) = e;
    }
}

// ---------------- per-tile prefetch register set ----------------
struct pref_t {
    float4 fv[8];   // feat2d tile slice (8 channels x 4 px)
    row_u g;        // gathered 3D feature half-row (32 bf16)
    float4 e;       // xy / lf3d extras (cp==0 lanes)
    float lfx, lfy; // lf2d at pixel (cp==0 lanes)
};

static __device__ __forceinline__ void tile_load(
    pref_t& P, const float* __restrict__ feat2d, const float* __restrict__ lf2d,
    const char* __restrict__ ptab, int b, int p_base, int w, int lane, int idx)
{
    const int ci = lane >> 3, qd = lane & 7;
    const int px0 = 32 * w + qd * 4;
#pragma unroll
    for (int cc = 0; cc < 8; cc++)
        P.fv[cc] = *(const float4*)(feat2d + (size_t)(b * CH + ci * 8 + cc) * HW + p_base + px0);
    const int cp = lane >> 5, j = lane & 31;
    const int n = 32 * w + j;
    const char* prow = ptab + ((size_t)b * NN + idx) * PT_ROW;
#pragma unroll
    for (int k = 0; k < 4; k++) P.g.q[k] = ((const uint4*)prow)[cp * 4 + k];
    if (cp == 0) {
        P.e = *(const float4*)(prow + 144);
        P.lfx = lf2d[(size_t)(b * 2 + 0) * HW + p_base + n];
        P.lfy = lf2d[(size_t)(b * 2 + 1) * HW + p_base + n];
    }
}

static __device__ __forceinline__ void tile_stage(
    const pref_t& P, unsigned short* F2, unsigned short* Xhi, int w, int lane)
{
    const int ci = lane >> 3, qd = lane & 7;
    const int px0 = 32 * w + qd * 4;
#pragma unroll
    for (int px = 0; px < 4; px++) {
        frag_u fr;
#pragma unroll
        for (int cc = 0; cc < 8; cc++)
            fr.u[cc] = f2bf(((const float*)&P.fv[cc])[px]);
        *(short8*)&F2[(px0 + px) * F2PITCH + ci * 8] = fr.v;
    }
    const int cp = lane >> 5, j = lane & 31;
    const int n = 32 * w + j;
    uint4* xp = (uint4*)&Xhi[n * XPITCH + cp * 32];
#pragma unroll
    for (int k = 0; k < 4; k++) xp[k] = P.g.q[k];
}

static __device__ __forceinline__ void tile_corr(
    const pref_t& P, const unsigned short* F2, float* offsS, float* auxS,
    int p_base, int w, int lane)
{
    const int cp = lane >> 5, j = lane & 31;
    const int n = 32 * w + j;
    const int p = p_base + n;
    frag_u f2v[4];
#pragma unroll
    for (int k = 0; k < 4; k++)
        f2v[k].v = *(const short8*)&F2[n * F2PITCH + cp * 32 + k * 8];
    float ca = 0.f;
#pragma unroll
    for (int i = 0; i < 32; i++)
        ca += bf2f(f2v[i >> 3].u[i & 7]) * bf2f(P.g.u[i]);
    ca += __shfl_xor(ca, 32);        // combine the two channel-halves in-wave
    if (cp == 0) {
        offsS[n] = P.e.x - (float)(p & 255);
        offsS[NT + n] = P.e.y - (float)(p >> 8);
        auxS[n] = ca * (1.0f / 64.0f);   // corr (f32 path)
        auxS[NT + n] = P.e.z - P.lfx;    // fcx
        auxS[2 * NT + n] = P.e.w - P.lfy;// fcy
    }
}

// ---------------- MFMA layer core (wave owns rows [32w, 32w+32), acc[4][2]) ----------------
template<int KT, int KROW, bool LO>
static __device__ __forceinline__ void layer_mfma(
    const unsigned short* __restrict__ wrow,
    const unsigned short* Xh, const unsigned short* Xl,
    int w, int ln, int q, f32x4 acc[4][2])
{
#pragma unroll
    for (int kt = 0; kt < KT; kt++) {
        const int kcol = kt * 32 + q * 8;
        short8 A[4];
#pragma unroll
        for (int mi = 0; mi < 4; mi++)
            A[mi] = *(const short8*)(wrow + (mi * 16 + ln) * KROW + kcol);
#pragma unroll
        for (int ni = 0; ni < 2; ni++) {
            const int nr = 32 * w + ni * 16 + ln;
            short8 bh = *(const short8*)(Xh + nr * XPITCH + kcol);
            short8 bl = bh;
            if (LO) bl = *(const short8*)(Xl + nr * LPITCH + kcol);
#pragma unroll
            for (int mi = 0; mi < 4; mi++) {
                acc[mi][ni] = __builtin_amdgcn_mfma_f32_16x16x32_bf16(A[mi], bh, acc[mi][ni], 0, 0, 0);
                if (LO)
                    acc[mi][ni] = __builtin_amdgcn_mfma_f32_16x16x32_bf16(A[mi], bl, acc[mi][ni], 0, 0, 0);
            }
        }
    }
}

static __device__ __forceinline__ void zero_acc(f32x4 acc[4][2]) {
#pragma unroll
    for (int mi = 0; mi < 4; mi++)
#pragma unroll
        for (int ni = 0; ni < 2; ni++)
#pragma unroll
            for (int r = 0; r < 4; r++) acc[mi][ni][r] = 0.f;
}

// epilogue: leaky(acc + bias [+ rank-5 f32 fix]) -> X hi/lo (wave-private rows)
static __device__ __forceinline__ void epi_x(
    f32x4 acc[4][2], const float* __restrict__ fws, int bofs, bool off_fix,
    const float* offsp, const float* auxp, unsigned short* Xh, unsigned short* Xl,
    int w, int ln, int q)
{
#pragma unroll
    for (int mi = 0; mi < 4; mi++) {
        const float4 bias = *(const float4*)(fws + bofs + mi * 16 + q * 4);
        float4 wox = bias, woy = bias, wco = bias, wfx = bias, wfy = bias;
        if (off_fix) {
            wox = *(const float4*)(fws + 256 + mi * 16 + q * 4);
            woy = *(const float4*)(fws + 320 + mi * 16 + q * 4);
            wco = *(const float4*)(fws + 384 + mi * 16 + q * 4);
            wfx = *(const float4*)(fws + 448 + mi * 16 + q * 4);
            wfy = *(const float4*)(fws + 512 + mi * 16 + q * 4);
        }
#pragma unroll
        for (int ni = 0; ni < 2; ni++) {
            const int nr = 32 * w + ni * 16 + ln;
            float ox = 0.f, oy = 0.f, co = 0.f, fx = 0.f, fy = 0.f;
            if (off_fix) {
                ox = offsp[nr]; oy = offsp[NT + nr];
                co = auxp[nr];  fx = auxp[NT + nr]; fy = auxp[2 * NT + nr];
            }
            unsigned int hh0 = 0, hh1 = 0, ll0 = 0, ll1 = 0;
#pragma unroll
            for (int r = 0; r < 4; r++) {
                float a = acc[mi][ni][r] + ((const float*)&bias)[r];
                if (off_fix) {
                    a += ((const float*)&wox)[r] * ox + ((const float*)&woy)[r] * oy;
                    a += ((const float*)&wco)[r] * co;
                    a += ((const float*)&wfx)[r] * fx + ((const float*)&wfy)[r] * fy;
                }
                a = fmaxf(a, 0.1f * a);
                const unsigned short hb = f2bf(a);
                const unsigned short lb = f2bf(a - bf2f(hb));
                if (r == 0) { hh0 = hb; ll0 = lb; }
                if (r == 1) { hh0 |= ((unsigned)hb) << 16; ll0 |= ((unsigned)lb) << 16; }
                if (r == 2) { hh1 = hb; ll1 = lb; }
                if (r == 3) { hh1 |= ((unsigned)hb) << 16; ll1 |= ((unsigned)lb) << 16; }
            }
            *(uint2*)&Xh[nr * XPITCH + mi * 16 + q * 4] = make_uint2(hh0, hh1);
            *(uint2*)&Xl[nr * LPITCH + mi * 16 + q * 4] = make_uint2(ll0, ll1);
        }
    }
}

// per-tile MLP chain + output store
static __device__ __forceinline__ void compute_tile(
    const unsigned short* Xhi, const unsigned short* Xlo, const unsigned short* F2,
    const float* offsS, const float* auxS,
    const unsigned short* __restrict__ wpk, const float* __restrict__ fws,
    float* __restrict__ out, int b, int p_base, int w, int ln, int q)
{
    f32x4 acc[4][2];
    // L1 (K=64, g only, X hi; corr/offset/flow enter via rank-5 f32 fix)
    zero_acc(acc);
    layer_mfma<2, 64, false>(wpk + W1OFS, Xhi, Xlo, w, ln, q, acc);
    epi_x(acc, fws, 0, true, offsS, auxS, (unsigned short*)Xhi, (unsigned short*)Xlo, w, ln, q);
    // L2
    zero_acc(acc);
    layer_mfma<2, 64, true>(wpk + W2OFS, Xhi, Xlo, w, ln, q, acc);
    epi_x(acc, fws, 64, false, offsS, auxS, (unsigned short*)Xhi, (unsigned short*)Xlo, w, ln, q);
    // L3
    zero_acc(acc);
    layer_mfma<2, 64, true>(wpk + W3OFS, Xhi, Xlo, w, ln, q, acc);
    epi_x(acc, fws, 128, false, offsS, auxS, (unsigned short*)Xhi, (unsigned short*)Xlo, w, ln, q);
    // Lf: k 0-63 = x3 (LDS, hi+lo), k 64-127 = feat2d tile (F2 LDS, hi only)
    zero_acc(acc);
    layer_mfma<2, 128, true>(wpk + WFOFS, Xhi, Xlo, w, ln, q, acc);
#pragma unroll
    for (int kt = 2; kt < 4; kt++) {
        const int kcol = kt * 32 + q * 8;
        short8 A[4];
#pragma unroll
        for (int mi = 0; mi < 4; mi++)
            A[mi] = *(const short8*)(wpk + WFOFS + (mi * 16 + ln) * 128 + kcol);
#pragma unroll
        for (int ni = 0; ni < 2; ni++) {
            const int nr = 32 * w + ni * 16 + ln;
            frag_u fh;
            fh.v = *(const short8*)&F2[nr * F2PITCH + (kt - 2) * 32 + q * 8];
#pragma unroll
            for (int mi = 0; mi < 4; mi++)
                acc[mi][ni] = __builtin_amdgcn_mfma_f32_16x16x32_bf16(A[mi], fh.v, acc[mi][ni], 0, 0, 0);
        }
    }
    // final epilogue -> out f32
#pragma unroll
    for (int mi = 0; mi < 4; mi++) {
        const float4 bias = *(const float4*)(fws + 192 + mi * 16 + q * 4);
#pragma unroll
        for (int ni = 0; ni < 2; ni++) {
#pragma unroll
            for (int r = 0; r < 4; r++) {
                float a = acc[mi][ni][r] + ((const float*)&bias)[r];
                a = fmaxf(a, 0.1f * a);
                const int m = mi * 16 + q * 4 + r;
                out[(size_t)(b * CH + m) * HW + p_base + 32 * w + ni * 16 + ln] = a;
            }
        }
    }
}

// ---------------- main fused kernel: 2-tile software pipeline, zero barriers ----------------
// Block owns 256 px = 2 tiles of 128. Tile 1's global loads (gather + feat2d) are issued
// into registers BEFORE tile 0's compute, hiding their ~1.4Kcy latency under the MLP chain.
// LDS buffers are time-multiplexed across tiles (wave-private rows, in-order DS pipe, no
// barriers needed). LDS = 57,856 B -> 2 blocks/CU, __launch_bounds__ (256,2) caps VGPR at 256.
__global__ __launch_bounds__(256, 2) void fuse(
    const float* __restrict__ feat2d, const float* __restrict__ lf2d,
    const int* __restrict__ nn,
    const unsigned short* __restrict__ wpk, const float* __restrict__ fws,
    const char* __restrict__ ptab,
    float* __restrict__ out)
{
    __shared__ unsigned short Xhi[NT * XPITCH];   // 18432 B
    __shared__ unsigned short Xlo[NT * LPITCH];   // 18432 B
    __shared__ unsigned short F2[NT * F2PITCH];   // 18432 B
    __shared__ float offsS[2 * NT];               //  1024 B
    __shared__ float auxS[3 * NT];                //  1536 B

    const int tid = threadIdx.x;
    const int w = tid >> 6, lane = tid & 63;
    const int q = lane >> 4, ln = lane & 15;
    const int b = blockIdx.y;
    const int p0 = blockIdx.x * TW;
    const int n = 32 * w + (lane & 31);

    // both tiles' gather indices up front (removes nn->gather dependency from tile 1)
    const int idx0 = nn[(size_t)b * HW + p0 + n];
    const int idx1 = nn[(size_t)b * HW + p0 + NT + n];

    pref_t P0, P1;
    tile_load(P0, feat2d, lf2d, ptab, b, p0, w, lane, idx0);
    tile_stage(P0, F2, Xhi, w, lane);
    // prefetch tile 1 while tile 0 computes
    tile_load(P1, feat2d, lf2d, ptab, b, p0 + NT, w, lane, idx1);
    tile_corr(P0, F2, offsS, auxS, p0, w, lane);
    compute_tile(Xhi, Xlo, F2, offsS, auxS, wpk, fws, out, b, p0, w, ln, q);
    // tile 1: loads landed long ago; stage + compute
    tile_stage(P1, F2, Xhi, w, lane);
    tile_corr(P1, F2, offsS, auxS, p0 + NT, w, lane);
    compute_tile(Xhi, Xlo, F2, offsS, auxS, wpk, fws, out, b, p0 + NT, w, ln, q);
}

// ---------------- fallback (R4, passed): used only if ws too small ----------------
__global__ __launch_bounds__(256) void fuse_slow(
    const float* __restrict__ feat2d, const float* __restrict__ lf2d,
    const float* __restrict__ xy, const float* __restrict__ feat3d,
    const float* __restrict__ lf3d, const int* __restrict__ nn,
    const float* __restrict__ w1, const float* __restrict__ b1,
    const float* __restrict__ w2, const float* __restrict__ b2,
    const float* __restrict__ w3, const float* __restrict__ b3,
    const float* __restrict__ wf, const float* __restrict__ bfv,
    float* __restrict__ out)
{
    const int p = blockIdx.x * 256 + threadIdx.x;
    const int b = blockIdx.y;
    const int idx = nn[(size_t)b * HW + p];
    const float* f3 = feat3d + (size_t)b * CH * NN + idx;
    float g[CH];
#pragma unroll
    for (int c = 0; c < CH; c++) g[c] = f3[(size_t)c * NN];
    const float fl3x = lf3d[(size_t)(b * 2 + 0) * NN + idx];
    const float fl3y = lf3d[(size_t)(b * 2 + 1) * NN + idx];
    const float xyx = xy[(size_t)(b * 2 + 0) * NN + idx];
    const float xyy = xy[(size_t)(b * 2 + 1) * NN + idx];
    const float* f2p = feat2d + (size_t)b * CH * HW + p;
    float corr = 0.f;
#pragma unroll
    for (int c = 0; c < CH; c++) corr += f2p[(size_t)c * HW] * g[c];
    corr *= (1.f / 64.f);
    float xin[69];
    xin[0] = corr;
    xin[1] = xyx - (float)(p & 255);
    xin[2] = xyy - (float)(p >> 8);
#pragma unroll
    for (int c = 0; c < CH; c++) xin[3 + c] = g[c];
    xin[67] = fl3x - lf2d[(size_t)(b * 2 + 0) * HW + p];
    xin[68] = fl3y - lf2d[(size_t)(b * 2 + 1) * HW + p];
    float x1[64], x2[64], x3[64], accv[64];
#pragma unroll
    for (int o = 0; o < 64; o++) {
        float a = b1[o];
#pragma unroll
        for (int k = 0; k < 69; k++) a += w1[o * 69 + k] * xin[k];
        x1[o] = (a >= 0.f) ? a : 0.1f * a;
    }
#pragma unroll
    for (int o = 0; o < 64; o++) {
        float a = b2[o];
#pragma unroll
        for (int k = 0; k < 64; k++) a += w2[o * 64 + k] * x1[k];
        x2[o] = (a >= 0.f) ? a : 0.1f * a;
    }
#pragma unroll
    for (int o = 0; o < 64; o++) {
        float a = b3[o];
#pragma unroll
        for (int k = 0; k < 64; k++) a += w3[o * 64 + k] * x2[k];
        x3[o] = (a >= 0.f) ? a : 0.1f * a;
    }
#pragma unroll
    for (int o = 0; o < 64; o++) {
        float a = bfv[o];
#pragma unroll
        for (int k = 0; k < 64; k++) a += wf[o * 128 + k] * x3[k];
        accv[o] = a;
    }
#pragma unroll
    for (int k = 0; k < 64; k++) {
        const float f = f2p[(size_t)k * HW];
#pragma unroll
        for (int o = 0; o < 64; o++) accv[o] += wf[o * 128 + 64 + k] * f;
    }
#pragma unroll
    for (int o = 0; o < 64; o++) {
        float a = accv[o];
        a = (a >= 0.f) ? a : 0.1f * a;
        out[(size_t)(b * CH + o) * HW + p] = a;
    }
}

extern "C" void kernel_launch(void* const* d_in, const int* in_sizes, int n_in,
                              void* d_out, int out_size, void* d_ws, size_t ws_size,
                              hipStream_t stream)
{
    const float* xy   = (const float*)d_in[0];
    const float* f2d  = (const float*)d_in[1];
    const float* f3d  = (const float*)d_in[2];
    const float* lf2d = (const float*)d_in[3];
    const float* lf3d = (const float*)d_in[4];
    const int*   nn   = (const int*)d_in[5];
    const float* w1 = (const float*)d_in[6];
    const float* b1 = (const float*)d_in[7];
    const float* w2 = (const float*)d_in[8];
    const float* b2 = (const float*)d_in[9];
    const float* w3 = (const float*)d_in[10];
    const float* b3 = (const float*)d_in[11];
    const float* wf = (const float*)d_in[12];
    const float* bf = (const float*)d_in[13];

    if (ws_size >= WS_NEED) {
        unsigned short* wpk = (unsigned short*)d_ws;
        float* fws = (float*)((char*)d_ws + FWS_BYTE);
        char* pt = (char*)d_ws + PTAB_BYTE;
        prep<<<dim3(NN / 64 + 5, BB), 256, 0, stream>>>(xy, f3d, lf3d,
                                                        w1, b1, w2, b2, w3, b3, wf, bf,
                                                        wpk, fws, pt);
        fuse<<<dim3(HW / TW, BB), 256, 0, stream>>>(f2d, lf2d, nn, wpk, fws, pt, (float*)d_out);
    } else {
        fuse_slow<<<dim3(HW / 256, BB), 256, 0, stream>>>(f2d, lf2d, xy, f3d, lf3d, nn,
                                                          w1, b1, w2, b2, w3, b3, wf, bf,
                                                          (float*)d_out);
    }
}

// Round 7
// 210.337 us; speedup vs baseline: 1.2609x; 1.0306x over previous
//
#include <hip/hip_runtime.h>

#define BB 4
#define CH 64
#define HW 65536
#define NN 16384
#define NT 128
#define TW 256
#define XPITCH 72
#define F2PITCH 72
#define W1OFS 0
#define W2OFS 4096
#define W3OFS 8192
#define WFOFS 12288
#define FWS_BYTE 46080
#define PTAB_BYTE 49152
#define PT_ROW 160
#define WS_NEED ((size_t)PTAB_BYTE + (size_t)BB * NN * PT_ROW)

typedef __attribute__((ext_vector_type(8))) short short8;
typedef __attribute__((ext_vector_type(4))) float f32x4;

union frag_u { unsigned short u[8]; short8 v; };
union frag2_u { unsigned short u[8]; unsigned int d[4]; short8 v; };
union row_u  { uint4 q[4]; unsigned short u[32]; };
union half_u { uint4 q[2]; unsigned short u[16]; };

static __device__ __forceinline__ unsigned short f2bf(float x) {
    unsigned int u = __float_as_uint(x);
    return (unsigned short)((u + 0x7fffu + ((u >> 16) & 1u)) >> 16);
}
static __device__ __forceinline__ float bf2f(unsigned short h) {
    return __uint_as_float(((unsigned int)h) << 16);
}
// packed f32->2xbf16 RTNE (identical rounding to f2bf)
static __device__ __forceinline__ unsigned int cvtpk(float a, float b) {
    unsigned int r;
    asm("v_cvt_pk_bf16_f32 %0, %1, %2" : "=v"(r) : "v"(a), "v"(b));
    return r;
}

// ---------------- merged prepass: weights (blocks >= NN/64) + point table ----------------
// fws layout (f32): 0 b1 | 64 b2 | 128 b3 | 192 bf | 256 w_ox | 320 w_oy |
//                   384 w_corr | 448 w_fx | 512 w_fy
__global__ __launch_bounds__(256) void prep(
    const float* __restrict__ xy, const float* __restrict__ f3d,
    const float* __restrict__ lf3d,
    const float* __restrict__ w1, const float* __restrict__ b1,
    const float* __restrict__ w2, const float* __restrict__ b2,
    const float* __restrict__ w3, const float* __restrict__ b3,
    const float* __restrict__ wf, const float* __restrict__ bf,
    unsigned short* __restrict__ wpk, float* __restrict__ fws,
    char* __restrict__ pt)
{
    const int t = threadIdx.x;
    const int bx = blockIdx.x;
    if (bx >= NN / 64) {
        if (blockIdx.y != 0) return;
        const int blk = bx - NN / 64;
        if (blk == 0) {
            for (int i = t; i < 64 * 64; i += 256) {
                const int m = i >> 6, k = i & 63;
                wpk[W1OFS + i] = f2bf(w1[m * 69 + 3 + k]);
            }
        } else if (blk == 1) {
            for (int i = t; i < 64 * 64; i += 256) wpk[W2OFS + i] = f2bf(w2[i]);
        } else if (blk == 2) {
            for (int i = t; i < 64 * 64; i += 256) wpk[W3OFS + i] = f2bf(w3[i]);
        } else if (blk == 3) {
            for (int i = t; i < 64 * 128; i += 256) wpk[WFOFS + i] = f2bf(wf[i]);
        } else if (t < 64) {
            fws[t]       = b1[t];
            fws[64 + t]  = b2[t];
            fws[128 + t] = b3[t];
            fws[192 + t] = bf[t];
            fws[256 + t] = w1[t * 69 + 1];   // offset-x column (f32 path)
            fws[320 + t] = w1[t * 69 + 2];   // offset-y column
            fws[384 + t] = w1[t * 69 + 0];   // corr column
            fws[448 + t] = w1[t * 69 + 67];  // flow-x column
            fws[512 + t] = w1[t * 69 + 68];  // flow-y column
        }
        return;
    }
    const int cq = t >> 6;
    const int l = t & 63;
    const int gn = bx * 64 + l;
    const int b = blockIdx.y;
    half_u r;
#pragma unroll
    for (int i = 0; i < 16; i++)
        r.u[i] = f2bf(f3d[(size_t)(b * CH + cq * 16 + i) * NN + gn]);
    char* row = pt + ((size_t)b * NN + gn) * PT_ROW;
    uint4* rq = (uint4*)row;
    rq[2 * cq] = r.q[0];
    rq[2 * cq + 1] = r.q[1];
    if (cq == 0) {
        float4 e;
        e.x = xy[(size_t)(b * 2 + 0) * NN + gn];
        e.y = xy[(size_t)(b * 2 + 1) * NN + gn];
        e.z = lf3d[(size_t)(b * 2 + 0) * NN + gn];
        e.w = lf3d[(size_t)(b * 2 + 1) * NN + gn];
        *(float4*)(row + 144) = e;
    }
}

// ---------------- per-tile prefetch register set ----------------
struct pref_t {
    float4 fv[8];   // feat2d tile slice (8 channels x 4 px)
    row_u g;        // gathered 3D feature half-row (32 bf16)
    float4 e;       // xy / lf3d extras (cp==0 lanes)
    float lfx, lfy; // lf2d at pixel (cp==0 lanes)
};

static __device__ __forceinline__ void tile_load(
    pref_t& P, const float* __restrict__ feat2d, const float* __restrict__ lf2d,
    const char* __restrict__ ptab, int b, int p_base, int w, int lane, int idx)
{
    const int ci = lane >> 3, qd = lane & 7;
    const int px0 = 32 * w + qd * 4;
#pragma unroll
    for (int cc = 0; cc < 8; cc++)
        P.fv[cc] = *(const float4*)(feat2d + (size_t)(b * CH + ci * 8 + cc) * HW + p_base + px0);
    const int cp = lane >> 5, j = lane & 31;
    const int n = 32 * w + j;
    const char* prow = ptab + ((size_t)b * NN + idx) * PT_ROW;
#pragma unroll
    for (int k = 0; k < 4; k++) P.g.q[k] = ((const uint4*)prow)[cp * 4 + k];
    if (cp == 0) {
        P.e = *(const float4*)(prow + 144);
        P.lfx = lf2d[(size_t)(b * 2 + 0) * HW + p_base + n];
        P.lfy = lf2d[(size_t)(b * 2 + 1) * HW + p_base + n];
    }
}

static __device__ __forceinline__ void tile_stage(
    const pref_t& P, unsigned short* F2, unsigned short* Xhi, int w, int lane)
{
    const int ci = lane >> 3, qd = lane & 7;
    const int px0 = 32 * w + qd * 4;
#pragma unroll
    for (int px = 0; px < 4; px++) {
        frag2_u fr;
#pragma unroll
        for (int cc = 0; cc < 4; cc++)
            fr.d[cc] = cvtpk(((const float*)&P.fv[2 * cc])[px], ((const float*)&P.fv[2 * cc + 1])[px]);
        *(short8*)&F2[(px0 + px) * F2PITCH + ci * 8] = fr.v;
    }
    const int cp = lane >> 5, j = lane & 31;
    const int n = 32 * w + j;
    uint4* xp = (uint4*)&Xhi[n * XPITCH + cp * 32];
#pragma unroll
    for (int k = 0; k < 4; k++) xp[k] = P.g.q[k];
}

static __device__ __forceinline__ void tile_corr(
    const pref_t& P, const unsigned short* F2, float* offsS, float* auxS,
    int p_base, int w, int lane)
{
    const int cp = lane >> 5, j = lane & 31;
    const int n = 32 * w + j;
    const int p = p_base + n;
    frag_u f2v[4];
#pragma unroll
    for (int k = 0; k < 4; k++)
        f2v[k].v = *(const short8*)&F2[n * F2PITCH + cp * 32 + k * 8];
    float ca = 0.f;
#pragma unroll
    for (int i = 0; i < 32; i++)
        ca += bf2f(f2v[i >> 3].u[i & 7]) * bf2f(P.g.u[i]);
    ca += __shfl_xor(ca, 32);
    if (cp == 0) {
        offsS[n] = P.e.x - (float)(p & 255);
        offsS[NT + n] = P.e.y - (float)(p >> 8);
        auxS[n] = ca * (1.0f / 64.0f);
        auxS[NT + n] = P.e.z - P.lfx;
        auxS[2 * NT + n] = P.e.w - P.lfy;
    }
}

// ---------------- L1 MFMA (B from LDS Xhi, hi only) ----------------
static __device__ __forceinline__ void layer_l1(
    const unsigned short* __restrict__ wrow, const unsigned short* Xh,
    int w, int ln, int q, f32x4 acc[4][2])
{
#pragma unroll
    for (int kt = 0; kt < 2; kt++) {
        const int kcol = kt * 32 + q * 8;
        short8 A[4];
#pragma unroll
        for (int mi = 0; mi < 4; mi++)
            A[mi] = *(const short8*)(wrow + (mi * 16 + ln) * 64 + kcol);
#pragma unroll
        for (int ni = 0; ni < 2; ni++) {
            const int nr = 32 * w + ni * 16 + ln;
            short8 bh = *(const short8*)(Xh + nr * XPITCH + kcol);
            __builtin_amdgcn_s_setprio(1);
#pragma unroll
            for (int mi = 0; mi < 4; mi++)
                acc[mi][ni] = __builtin_amdgcn_mfma_f32_16x16x32_bf16(A[mi], bh, acc[mi][ni], 0, 0, 0);
            __builtin_amdgcn_s_setprio(0);
        }
    }
}

// ---------------- reg-exchange layer: B built from prev layer's pk via ds_bpermute ----------
// lane (q,ln) target u32 p of B(kt,ni) = pk[mi=kt*2+(q>>1)][ni][t=p&1]
// pulled from lane ((q&1)*2+(p>>1))*16+ln
template<int KROW>
static __device__ __forceinline__ void layer_reg(
    const unsigned short* __restrict__ wrow,
    const unsigned int pkH[4][2][2], const unsigned int pkL[4][2][2],
    int srcA, int srcB, int qh, int ln, int q, f32x4 acc[4][2])
{
#pragma unroll
    for (int kt = 0; kt < 2; kt++) {
        const int kcol = kt * 32 + q * 8;
        short8 A[4];
#pragma unroll
        for (int mi = 0; mi < 4; mi++)
            A[mi] = *(const short8*)(wrow + (mi * 16 + ln) * KROW + kcol);
#pragma unroll
        for (int ni = 0; ni < 2; ni++) {
            frag2_u bh, bl;
#pragma unroll
            for (int p = 0; p < 4; p++) {
                const int src = (p >> 1) ? srcB : srcA;
                const unsigned h0 = (unsigned)__builtin_amdgcn_ds_bpermute(src, (int)pkH[kt * 2 + 0][ni][p & 1]);
                const unsigned h1 = (unsigned)__builtin_amdgcn_ds_bpermute(src, (int)pkH[kt * 2 + 1][ni][p & 1]);
                bh.d[p] = qh ? h1 : h0;
                const unsigned l0 = (unsigned)__builtin_amdgcn_ds_bpermute(src, (int)pkL[kt * 2 + 0][ni][p & 1]);
                const unsigned l1 = (unsigned)__builtin_amdgcn_ds_bpermute(src, (int)pkL[kt * 2 + 1][ni][p & 1]);
                bl.d[p] = qh ? l1 : l0;
            }
            __builtin_amdgcn_s_setprio(1);
#pragma unroll
            for (int mi = 0; mi < 4; mi++) {
                acc[mi][ni] = __builtin_amdgcn_mfma_f32_16x16x32_bf16(A[mi], bh.v, acc[mi][ni], 0, 0, 0);
                acc[mi][ni] = __builtin_amdgcn_mfma_f32_16x16x32_bf16(A[mi], bl.v, acc[mi][ni], 0, 0, 0);
            }
            __builtin_amdgcn_s_setprio(0);
        }
    }
}

static __device__ __forceinline__ void zero_acc(f32x4 acc[4][2]) {
#pragma unroll
    for (int mi = 0; mi < 4; mi++)
#pragma unroll
        for (int ni = 0; ni < 2; ni++)
#pragma unroll
            for (int r = 0; r < 4; r++) acc[mi][ni][r] = 0.f;
}

// epilogue: leaky(acc + bias [+ rank-5 f32 fix]) -> packed bf16 hi/lo rails in registers
static __device__ __forceinline__ void epi_pack(
    f32x4 acc[4][2], const float* __restrict__ fws, int bofs, bool off_fix,
    const float* offsp, const float* auxp,
    unsigned int pkH[4][2][2], unsigned int pkL[4][2][2],
    int w, int ln, int q)
{
#pragma unroll
    for (int mi = 0; mi < 4; mi++) {
        const float4 bias = *(const float4*)(fws + bofs + mi * 16 + q * 4);
        float4 wox = bias, woy = bias, wco = bias, wfx = bias, wfy = bias;
        if (off_fix) {
            wox = *(const float4*)(fws + 256 + mi * 16 + q * 4);
            woy = *(const float4*)(fws + 320 + mi * 16 + q * 4);
            wco = *(const float4*)(fws + 384 + mi * 16 + q * 4);
            wfx = *(const float4*)(fws + 448 + mi * 16 + q * 4);
            wfy = *(const float4*)(fws + 512 + mi * 16 + q * 4);
        }
#pragma unroll
        for (int ni = 0; ni < 2; ni++) {
            const int nr = 32 * w + ni * 16 + ln;
            float ox = 0.f, oy = 0.f, co = 0.f, fx = 0.f, fy = 0.f;
            if (off_fix) {
                ox = offsp[nr]; oy = offsp[NT + nr];
                co = auxp[nr];  fx = auxp[NT + nr]; fy = auxp[2 * NT + nr];
            }
            float av[4];
#pragma unroll
            for (int r = 0; r < 4; r++) {
                float a = acc[mi][ni][r] + ((const float*)&bias)[r];
                if (off_fix) {
                    a += ((const float*)&wox)[r] * ox + ((const float*)&woy)[r] * oy;
                    a += ((const float*)&wco)[r] * co;
                    a += ((const float*)&wfx)[r] * fx + ((const float*)&wfy)[r] * fy;
                }
                av[r] = fmaxf(a, 0.1f * a);
            }
#pragma unroll
            for (int t = 0; t < 2; t++) {
                const unsigned hh = cvtpk(av[2 * t], av[2 * t + 1]);
                const float l0 = av[2 * t]     - __uint_as_float(hh << 16);
                const float l1 = av[2 * t + 1] - __uint_as_float(hh & 0xffff0000u);
                pkH[mi][ni][t] = hh;
                pkL[mi][ni][t] = cvtpk(l0, l1);
            }
        }
    }
}

// per-tile MLP chain + output store (activations flow in registers between layers)
static __device__ __forceinline__ void compute_tile(
    const unsigned short* Xhi, const unsigned short* F2,
    const float* offsS, const float* auxS,
    const unsigned short* __restrict__ wpk, const float* __restrict__ fws,
    float* __restrict__ out, int b, int p_base, int w, int ln, int q,
    int srcA, int srcB, int qh)
{
    unsigned int pkH[4][2][2], pkL[4][2][2];
    f32x4 acc[4][2];
    // L1 (K=64, g only; corr/offset/flow enter via rank-5 f32 fix)
    zero_acc(acc);
    layer_l1(wpk + W1OFS, Xhi, w, ln, q, acc);
    epi_pack(acc, fws, 0, true, offsS, auxS, pkH, pkL, w, ln, q);
    // L2
    zero_acc(acc);
    layer_reg<64>(wpk + W2OFS, pkH, pkL, srcA, srcB, qh, ln, q, acc);
    epi_pack(acc, fws, 64, false, offsS, auxS, pkH, pkL, w, ln, q);
    // L3
    zero_acc(acc);
    layer_reg<64>(wpk + W3OFS, pkH, pkL, srcA, srcB, qh, ln, q, acc);
    epi_pack(acc, fws, 128, false, offsS, auxS, pkH, pkL, w, ln, q);
    // Lf: k 0-63 = x3 (reg exchange, hi+lo), k 64-127 = feat2d tile (F2 LDS, hi only)
    zero_acc(acc);
    layer_reg<128>(wpk + WFOFS, pkH, pkL, srcA, srcB, qh, ln, q, acc);
#pragma unroll
    for (int kt = 2; kt < 4; kt++) {
        const int kcol = kt * 32 + q * 8;
        short8 A[4];
#pragma unroll
        for (int mi = 0; mi < 4; mi++)
            A[mi] = *(const short8*)(wpk + WFOFS + (mi * 16 + ln) * 128 + kcol);
#pragma unroll
        for (int ni = 0; ni < 2; ni++) {
            const int nr = 32 * w + ni * 16 + ln;
            frag_u fh;
            fh.v = *(const short8*)&F2[nr * F2PITCH + (kt - 2) * 32 + q * 8];
            __builtin_amdgcn_s_setprio(1);
#pragma unroll
            for (int mi = 0; mi < 4; mi++)
                acc[mi][ni] = __builtin_amdgcn_mfma_f32_16x16x32_bf16(A[mi], fh.v, acc[mi][ni], 0, 0, 0);
            __builtin_amdgcn_s_setprio(0);
        }
    }
    // final epilogue -> out f32
#pragma unroll
    for (int mi = 0; mi < 4; mi++) {
        const float4 bias = *(const float4*)(fws + 192 + mi * 16 + q * 4);
#pragma unroll
        for (int ni = 0; ni < 2; ni++) {
#pragma unroll
            for (int r = 0; r < 4; r++) {
                float a = acc[mi][ni][r] + ((const float*)&bias)[r];
                a = fmaxf(a, 0.1f * a);
                const int m = mi * 16 + q * 4 + r;
                out[(size_t)(b * CH + m) * HW + p_base + 32 * w + ni * 16 + ln] = a;
            }
        }
    }
}

// ---------------- main fused kernel: 2-tile pipeline, zero barriers, reg-exchange MLP ------
// LDS = 39,424 B. Activations pass layer-to-layer via ds_bpermute (no LDS RAW round-trip).
__global__ __launch_bounds__(256, 2) void fuse(
    const float* __restrict__ feat2d, const float* __restrict__ lf2d,
    const int* __restrict__ nn,
    const unsigned short* __restrict__ wpk, const float* __restrict__ fws,
    const char* __restrict__ ptab,
    float* __restrict__ out)
{
    __shared__ unsigned short Xhi[NT * XPITCH];   // 18432 B (L1 gather stage)
    __shared__ unsigned short F2[NT * F2PITCH];   // 18432 B (feat2d tile bf16)
    __shared__ float offsS[2 * NT];               //  1024 B
    __shared__ float auxS[3 * NT];                //  1536 B

    const int tid = threadIdx.x;
    const int w = tid >> 6, lane = tid & 63;
    const int q = lane >> 4, ln = lane & 15;
    const int b = blockIdx.y;
    const int p0 = blockIdx.x * TW;
    const int n = 32 * w + (lane & 31);

    // bpermute byte addresses for the q-group exchange (src lanes (q&1)*2*16+ln, +16)
    const int srcA = (((lane >> 4) & 1) * 32 + ln) * 4;
    const int srcB = srcA + 64;
    const int qh = q >> 1;

    const int idx0 = nn[(size_t)b * HW + p0 + n];
    const int idx1 = nn[(size_t)b * HW + p0 + NT + n];

    pref_t P0, P1;
    tile_load(P0, feat2d, lf2d, ptab, b, p0, w, lane, idx0);
    tile_stage(P0, F2, Xhi, w, lane);
    // prefetch tile 1 while tile 0 computes
    tile_load(P1, feat2d, lf2d, ptab, b, p0 + NT, w, lane, idx1);
    tile_corr(P0, F2, offsS, auxS, p0, w, lane);
    compute_tile(Xhi, F2, offsS, auxS, wpk, fws, out, b, p0, w, ln, q, srcA, srcB, qh);
    tile_stage(P1, F2, Xhi, w, lane);
    tile_corr(P1, F2, offsS, auxS, p0 + NT, w, lane);
    compute_tile(Xhi, F2, offsS, auxS, wpk, fws, out, b, p0 + NT, w, ln, q, srcA, srcB, qh);
}

// ---------------- fallback: used only if ws too small ----------------
__global__ __launch_bounds__(256) void fuse_slow(
    const float* __restrict__ feat2d, const float* __restrict__ lf2d,
    const float* __restrict__ xy, const float* __restrict__ feat3d,
    const float* __restrict__ lf3d, const int* __restrict__ nn,
    const float* __restrict__ w1, const float* __restrict__ b1,
    const float* __restrict__ w2, const float* __restrict__ b2,
    const float* __restrict__ w3, const float* __restrict__ b3,
    const float* __restrict__ wf, const float* __restrict__ bfv,
    float* __restrict__ out)
{
    const int p = blockIdx.x * 256 + threadIdx.x;
    const int b = blockIdx.y;
    const int idx = nn[(size_t)b * HW + p];
    const float* f3 = feat3d + (size_t)b * CH * NN + idx;
    float g[CH];
#pragma unroll
    for (int c = 0; c < CH; c++) g[c] = f3[(size_t)c * NN];
    const float fl3x = lf3d[(size_t)(b * 2 + 0) * NN + idx];
    const float fl3y = lf3d[(size_t)(b * 2 + 1) * NN + idx];
    const float xyx = xy[(size_t)(b * 2 + 0) * NN + idx];
    const float xyy = xy[(size_t)(b * 2 + 1) * NN + idx];
    const float* f2p = feat2d + (size_t)b * CH * HW + p;
    float corr = 0.f;
#pragma unroll
    for (int c = 0; c < CH; c++) corr += f2p[(size_t)c * HW] * g[c];
    corr *= (1.f / 64.f);
    float xin[69];
    xin[0] = corr;
    xin[1] = xyx - (float)(p & 255);
    xin[2] = xyy - (float)(p >> 8);
#pragma unroll
    for (int c = 0; c < CH; c++) xin[3 + c] = g[c];
    xin[67] = fl3x - lf2d[(size_t)(b * 2 + 0) * HW + p];
    xin[68] = fl3y - lf2d[(size_t)(b * 2 + 1) * HW + p];
    float x1[64], x2[64], x3[64], accv[64];
#pragma unroll
    for (int o = 0; o < 64; o++) {
        float a = b1[o];
#pragma unroll
        for (int k = 0; k < 69; k++) a += w1[o * 69 + k] * xin[k];
        x1[o] = (a >= 0.f) ? a : 0.1f * a;
    }
#pragma unroll
    for (int o = 0; o < 64; o++) {
        float a = b2[o];
#pragma unroll
        for (int k = 0; k < 64; k++) a += w2[o * 64 + k] * x1[k];
        x2[o] = (a >= 0.f) ? a : 0.1f * a;
    }
#pragma unroll
    for (int o = 0; o < 64; o++) {
        float a = b3[o];
#pragma unroll
        for (int k = 0; k < 64; k++) a += w3[o * 64 + k] * x2[k];
        x3[o] = (a >= 0.f) ? a : 0.1f * a;
    }
#pragma unroll
    for (int o = 0; o < 64; o++) {
        float a = bfv[o];
#pragma unroll
        for (int k = 0; k < 64; k++) a += wf[o * 128 + k] * x3[k];
        accv[o] = a;
    }
#pragma unroll
    for (int k = 0; k < 64; k++) {
        const float f = f2p[(size_t)k * HW];
#pragma unroll
        for (int o = 0; o < 64; o++) accv[o] += wf[o * 128 + 64 + k] * f;
    }
#pragma unroll
    for (int o = 0; o < 64; o++) {
        float a = accv[o];
        a = (a >= 0.f) ? a : 0.1f * a;
        out[(size_t)(b * CH + o) * HW + p] = a;
    }
}

extern "C" void kernel_launch(void* const* d_in, const int* in_sizes, int n_in,
                              void* d_out, int out_size, void* d_ws, size_t ws_size,
                              hipStream_t stream)
{
    const float* xy   = (const float*)d_in[0];
    const float* f2d  = (const float*)d_in[1];
    const float* f3d  = (const float*)d_in[2];
    const float* lf2d = (const float*)d_in[3];
    const float* lf3d = (const float*)d_in[4];
    const int*   nn   = (const int*)d_in[5];
    const float* w1 = (const float*)d_in[6];
    const float* b1 = (const float*)d_in[7];
    const float* w2 = (const float*)d_in[8];
    const float* b2 = (const float*)d_in[9];
    const float* w3 = (const float*)d_in[10];
    const float* b3 = (const float*)d_in[11];
    const float* wf = (const float*)d_in[12];
    const float* bf = (const float*)d_in[13];

    if (ws_size >= WS_NEED) {
        unsigned short* wpk = (unsigned short*)d_ws;
        float* fws = (float*)((char*)d_ws + FWS_BYTE);
        char* pt = (char*)d_ws + PTAB_BYTE;
        prep<<<dim3(NN / 64 + 5, BB), 256, 0, stream>>>(xy, f3d, lf3d,
                                                        w1, b1, w2, b2, w3, b3, wf, bf,
                                                        wpk, fws, pt);
        fuse<<<dim3(HW / TW, BB), 256, 0, stream>>>(f2d, lf2d, nn, wpk, fws, pt, (float*)d_out);
    } else {
        fuse_slow<<<dim3(HW / 256, BB), 256, 0, stream>>>(f2d, lf2d, xy, f3d, lf3d, nn,
                                                          w1, b1, w2, b2, w3, b3, wf, bf,
                                                          (float*)d_out);
    }
}

// Round 8
// 201.205 us; speedup vs baseline: 1.3181x; 1.0454x over previous
//
#include <hip/hip_runtime.h>

#define BB 4
#define CH 64
#define HW 65536
#define NN 16384
#define NT 128
#define TW 256
#define XPITCH 72
#define F2PITCH 72
#define W1OFS 0
#define W2OFS 4096
#define W3OFS 8192
#define WFOFS 12288
#define FWS_BYTE 46080
#define PTAB_BYTE 49152
#define PT_ROW 160
#define WS_NEED ((size_t)PTAB_BYTE + (size_t)BB * NN * PT_ROW)

typedef __attribute__((ext_vector_type(8))) short short8;
typedef __attribute__((ext_vector_type(4))) float f32x4;

union frag_u { unsigned short u[8]; short8 v; };
union frag2_u { unsigned short u[8]; unsigned int d[4]; short8 v; };
union row_u  { uint4 q[4]; unsigned short u[32]; };
union half_u { uint4 q[2]; unsigned short u[16]; };

static __device__ __forceinline__ unsigned short f2bf(float x) {
    unsigned int u = __float_as_uint(x);
    return (unsigned short)((u + 0x7fffu + ((u >> 16) & 1u)) >> 16);
}
static __device__ __forceinline__ float bf2f(unsigned short h) {
    return __uint_as_float(((unsigned int)h) << 16);
}
// packed f32->2xbf16 RTNE (identical rounding to f2bf)
static __device__ __forceinline__ unsigned int cvtpk(float a, float b) {
    unsigned int r;
    asm("v_cvt_pk_bf16_f32 %0, %1, %2" : "=v"(r) : "v"(a), "v"(b));
    return r;
}

// ---------------- merged prepass: weights (blocks >= NN/64) + point table ----------------
// fws layout (f32): 0 b1 | 64 b2 | 128 b3 | 192 bf | 256 w_ox | 320 w_oy |
//                   384 w_corr | 448 w_fx | 512 w_fy
__global__ __launch_bounds__(256) void prep(
    const float* __restrict__ xy, const float* __restrict__ f3d,
    const float* __restrict__ lf3d,
    const float* __restrict__ w1, const float* __restrict__ b1,
    const float* __restrict__ w2, const float* __restrict__ b2,
    const float* __restrict__ w3, const float* __restrict__ b3,
    const float* __restrict__ wf, const float* __restrict__ bf,
    unsigned short* __restrict__ wpk, float* __restrict__ fws,
    char* __restrict__ pt)
{
    const int t = threadIdx.x;
    const int bx = blockIdx.x;
    if (bx >= NN / 64) {
        if (blockIdx.y != 0) return;
        const int blk = bx - NN / 64;
        if (blk == 0) {
            for (int i = t; i < 64 * 64; i += 256) {
                const int m = i >> 6, k = i & 63;
                wpk[W1OFS + i] = f2bf(w1[m * 69 + 3 + k]);
            }
        } else if (blk == 1) {
            for (int i = t; i < 64 * 64; i += 256) wpk[W2OFS + i] = f2bf(w2[i]);
        } else if (blk == 2) {
            for (int i = t; i < 64 * 64; i += 256) wpk[W3OFS + i] = f2bf(w3[i]);
        } else if (blk == 3) {
            for (int i = t; i < 64 * 128; i += 256) wpk[WFOFS + i] = f2bf(wf[i]);
        } else if (t < 64) {
            fws[t]       = b1[t];
            fws[64 + t]  = b2[t];
            fws[128 + t] = b3[t];
            fws[192 + t] = bf[t];
            fws[256 + t] = w1[t * 69 + 1];   // offset-x column (f32 path)
            fws[320 + t] = w1[t * 69 + 2];   // offset-y column
            fws[384 + t] = w1[t * 69 + 0];   // corr column
            fws[448 + t] = w1[t * 69 + 67];  // flow-x column
            fws[512 + t] = w1[t * 69 + 68];  // flow-y column
        }
        return;
    }
    const int cq = t >> 6;
    const int l = t & 63;
    const int gn = bx * 64 + l;
    const int b = blockIdx.y;
    half_u r;
#pragma unroll
    for (int i = 0; i < 16; i++)
        r.u[i] = f2bf(f3d[(size_t)(b * CH + cq * 16 + i) * NN + gn]);
    char* row = pt + ((size_t)b * NN + gn) * PT_ROW;
    uint4* rq = (uint4*)row;
    rq[2 * cq] = r.q[0];
    rq[2 * cq + 1] = r.q[1];
    if (cq == 0) {
        float4 e;
        e.x = xy[(size_t)(b * 2 + 0) * NN + gn];
        e.y = xy[(size_t)(b * 2 + 1) * NN + gn];
        e.z = lf3d[(size_t)(b * 2 + 0) * NN + gn];
        e.w = lf3d[(size_t)(b * 2 + 1) * NN + gn];
        *(float4*)(row + 144) = e;
    }
}

// ---------------- weight staging: global wpk -> LDS, XOR-swizzled rows ----------------
// layout: W1@0, W2@4096, W3@8192 ([64][64], row=128B), WF@12288 ([64][128], row=256B)
// byte addr = base + row*RB + (colbyte ^ ((row&7)<<4)); bijective per row, kills the
// 16-way bank conflict of stride-128B row-major ds_read_b128 (G4 / T2).
static __device__ __forceinline__ void wstage(
    const unsigned short* __restrict__ wpk, unsigned short* wl, int tid)
{
#pragma unroll
    for (int m = 0; m < 3; m++) {
        const char* g = (const char*)(wpk + m * 4096);
        char* l = (char*)(wl + m * 4096);
        for (int i = tid; i < 512; i += 256) {   // 64 rows x 8 16B-chunks
            const int row = i >> 3, cb = (i & 7) * 16;
            const uint4 v = *(const uint4*)(g + row * 128 + cb);
            *(uint4*)(l + row * 128 + (cb ^ ((row & 7) << 4))) = v;
        }
    }
    {
        const char* g = (const char*)(wpk + WFOFS);
        char* l = (char*)(wl + WFOFS);
        for (int i = tid; i < 1024; i += 256) {  // 64 rows x 16 16B-chunks
            const int row = i >> 4, cb = (i & 15) * 16;
            const uint4 v = *(const uint4*)(g + row * 256 + cb);
            *(uint4*)(l + row * 256 + (cb ^ ((row & 7) << 4))) = v;
        }
    }
}

// ---------------- per-tile prefetch register set ----------------
struct pref_t {
    float4 fv[8];   // feat2d tile slice (8 channels x 4 px)
    row_u g;        // gathered 3D feature half-row (32 bf16)
    float4 e;       // xy / lf3d extras (cp==0 lanes)
    float lfx, lfy; // lf2d at pixel (cp==0 lanes)
};

static __device__ __forceinline__ void tile_load(
    pref_t& P, const float* __restrict__ feat2d, const float* __restrict__ lf2d,
    const char* __restrict__ ptab, int b, int p_base, int w, int lane, int idx)
{
    const int ci = lane >> 3, qd = lane & 7;
    const int px0 = 32 * w + qd * 4;
#pragma unroll
    for (int cc = 0; cc < 8; cc++)
        P.fv[cc] = *(const float4*)(feat2d + (size_t)(b * CH + ci * 8 + cc) * HW + p_base + px0);
    const int cp = lane >> 5, j = lane & 31;
    const int n = 32 * w + j;
    const char* prow = ptab + ((size_t)b * NN + idx) * PT_ROW;
#pragma unroll
    for (int k = 0; k < 4; k++) P.g.q[k] = ((const uint4*)prow)[cp * 4 + k];
    if (cp == 0) {
        P.e = *(const float4*)(prow + 144);
        P.lfx = lf2d[(size_t)(b * 2 + 0) * HW + p_base + n];
        P.lfy = lf2d[(size_t)(b * 2 + 1) * HW + p_base + n];
    }
}

static __device__ __forceinline__ void tile_stage(
    const pref_t& P, unsigned short* F2, unsigned short* Xhi, int w, int lane)
{
    const int ci = lane >> 3, qd = lane & 7;
    const int px0 = 32 * w + qd * 4;
#pragma unroll
    for (int px = 0; px < 4; px++) {
        frag2_u fr;
#pragma unroll
        for (int cc = 0; cc < 4; cc++)
            fr.d[cc] = cvtpk(((const float*)&P.fv[2 * cc])[px], ((const float*)&P.fv[2 * cc + 1])[px]);
        *(short8*)&F2[(px0 + px) * F2PITCH + ci * 8] = fr.v;
    }
    const int cp = lane >> 5, j = lane & 31;
    const int n = 32 * w + j;
    uint4* xp = (uint4*)&Xhi[n * XPITCH + cp * 32];
#pragma unroll
    for (int k = 0; k < 4; k++) xp[k] = P.g.q[k];
}

static __device__ __forceinline__ void tile_corr(
    const pref_t& P, const unsigned short* F2, float* offsS, float* auxS,
    int p_base, int w, int lane)
{
    const int cp = lane >> 5, j = lane & 31;
    const int n = 32 * w + j;
    const int p = p_base + n;
    frag_u f2v[4];
#pragma unroll
    for (int k = 0; k < 4; k++)
        f2v[k].v = *(const short8*)&F2[n * F2PITCH + cp * 32 + k * 8];
    float ca = 0.f;
#pragma unroll
    for (int i = 0; i < 32; i++)
        ca += bf2f(f2v[i >> 3].u[i & 7]) * bf2f(P.g.u[i]);
    ca += __shfl_xor(ca, 32);
    if (cp == 0) {
        offsS[n] = P.e.x - (float)(p & 255);
        offsS[NT + n] = P.e.y - (float)(p >> 8);
        auxS[n] = ca * (1.0f / 64.0f);
        auxS[NT + n] = P.e.z - P.lfx;
        auxS[2 * NT + n] = P.e.w - P.lfy;
    }
}

// ---------------- L1 MFMA (A from LDS weights swizzled, B from LDS Xhi, hi only) ----------
static __device__ __forceinline__ void layer_l1(
    const unsigned short* wrow, const unsigned short* Xh,
    int w, int ln, int q, int swz, f32x4 acc[4][2])
{
#pragma unroll
    for (int kt = 0; kt < 2; kt++) {
        const int kb = (kt * 32 + q * 8) * 2;
        short8 A[4];
#pragma unroll
        for (int mi = 0; mi < 4; mi++)
            A[mi] = *(const short8*)((const char*)wrow + (mi * 16 + ln) * 128 + (kb ^ swz));
#pragma unroll
        for (int ni = 0; ni < 2; ni++) {
            const int nr = 32 * w + ni * 16 + ln;
            short8 bh = *(const short8*)(Xh + nr * XPITCH + kt * 32 + q * 8);
            __builtin_amdgcn_s_setprio(1);
#pragma unroll
            for (int mi = 0; mi < 4; mi++)
                acc[mi][ni] = __builtin_amdgcn_mfma_f32_16x16x32_bf16(A[mi], bh, acc[mi][ni], 0, 0, 0);
            __builtin_amdgcn_s_setprio(0);
        }
    }
}

// ---------------- reg-exchange layer: A from LDS weights, B via ds_bpermute ----------------
// lane (q,ln) target u32 p of B(kt,ni) = pk[mi=kt*2+(q>>1)][ni][t=p&1]
// pulled from lane ((q&1)*2+(p>>1))*16+ln
template<int RB>   // weight row bytes (128 or 256)
static __device__ __forceinline__ void layer_reg(
    const unsigned short* wrow,
    const unsigned int pkH[4][2][2], const unsigned int pkL[4][2][2],
    int srcA, int srcB, int qh, int ln, int q, int swz, f32x4 acc[4][2])
{
#pragma unroll
    for (int kt = 0; kt < 2; kt++) {
        const int kb = (kt * 32 + q * 8) * 2;
        short8 A[4];
#pragma unroll
        for (int mi = 0; mi < 4; mi++)
            A[mi] = *(const short8*)((const char*)wrow + (mi * 16 + ln) * RB + (kb ^ swz));
#pragma unroll
        for (int ni = 0; ni < 2; ni++) {
            frag2_u bh, bl;
#pragma unroll
            for (int p = 0; p < 4; p++) {
                const int src = (p >> 1) ? srcB : srcA;
                const unsigned h0 = (unsigned)__builtin_amdgcn_ds_bpermute(src, (int)pkH[kt * 2 + 0][ni][p & 1]);
                const unsigned h1 = (unsigned)__builtin_amdgcn_ds_bpermute(src, (int)pkH[kt * 2 + 1][ni][p & 1]);
                bh.d[p] = qh ? h1 : h0;
                const unsigned l0 = (unsigned)__builtin_amdgcn_ds_bpermute(src, (int)pkL[kt * 2 + 0][ni][p & 1]);
                const unsigned l1 = (unsigned)__builtin_amdgcn_ds_bpermute(src, (int)pkL[kt * 2 + 1][ni][p & 1]);
                bl.d[p] = qh ? l1 : l0;
            }
            __builtin_amdgcn_s_setprio(1);
#pragma unroll
            for (int mi = 0; mi < 4; mi++) {
                acc[mi][ni] = __builtin_amdgcn_mfma_f32_16x16x32_bf16(A[mi], bh.v, acc[mi][ni], 0, 0, 0);
                acc[mi][ni] = __builtin_amdgcn_mfma_f32_16x16x32_bf16(A[mi], bl.v, acc[mi][ni], 0, 0, 0);
            }
            __builtin_amdgcn_s_setprio(0);
        }
    }
}

static __device__ __forceinline__ void zero_acc(f32x4 acc[4][2]) {
#pragma unroll
    for (int mi = 0; mi < 4; mi++)
#pragma unroll
        for (int ni = 0; ni < 2; ni++)
#pragma unroll
            for (int r = 0; r < 4; r++) acc[mi][ni][r] = 0.f;
}

// epilogue: leaky(acc + bias [+ rank-5 f32 fix]) -> packed bf16 hi/lo rails in registers
static __device__ __forceinline__ void epi_pack(
    f32x4 acc[4][2], const float* __restrict__ fws, int bofs, bool off_fix,
    const float* offsp, const float* auxp,
    unsigned int pkH[4][2][2], unsigned int pkL[4][2][2],
    int w, int ln, int q)
{
#pragma unroll
    for (int mi = 0; mi < 4; mi++) {
        const float4 bias = *(const float4*)(fws + bofs + mi * 16 + q * 4);
        float4 wox = bias, woy = bias, wco = bias, wfx = bias, wfy = bias;
        if (off_fix) {
            wox = *(const float4*)(fws + 256 + mi * 16 + q * 4);
            woy = *(const float4*)(fws + 320 + mi * 16 + q * 4);
            wco = *(const float4*)(fws + 384 + mi * 16 + q * 4);
            wfx = *(const float4*)(fws + 448 + mi * 16 + q * 4);
            wfy = *(const float4*)(fws + 512 + mi * 16 + q * 4);
        }
#pragma unroll
        for (int ni = 0; ni < 2; ni++) {
            const int nr = 32 * w + ni * 16 + ln;
            float ox = 0.f, oy = 0.f, co = 0.f, fx = 0.f, fy = 0.f;
            if (off_fix) {
                ox = offsp[nr]; oy = offsp[NT + nr];
                co = auxp[nr];  fx = auxp[NT + nr]; fy = auxp[2 * NT + nr];
            }
            float av[4];
#pragma unroll
            for (int r = 0; r < 4; r++) {
                float a = acc[mi][ni][r] + ((const float*)&bias)[r];
                if (off_fix) {
                    a += ((const float*)&wox)[r] * ox + ((const float*)&woy)[r] * oy;
                    a += ((const float*)&wco)[r] * co;
                    a += ((const float*)&wfx)[r] * fx + ((const float*)&wfy)[r] * fy;
                }
                av[r] = fmaxf(a, 0.1f * a);
            }
#pragma unroll
            for (int t = 0; t < 2; t++) {
                const unsigned hh = cvtpk(av[2 * t], av[2 * t + 1]);
                const float l0 = av[2 * t]     - __uint_as_float(hh << 16);
                const float l1 = av[2 * t + 1] - __uint_as_float(hh & 0xffff0000u);
                pkH[mi][ni][t] = hh;
                pkL[mi][ni][t] = cvtpk(l0, l1);
            }
        }
    }
}

// per-tile MLP chain + output store (activations flow in registers between layers)
static __device__ __forceinline__ void compute_tile(
    const unsigned short* Xhi, const unsigned short* F2,
    const float* offsS, const float* auxS,
    const unsigned short* wl, const float* __restrict__ fws,
    float* __restrict__ out, int b, int p_base, int w, int ln, int q,
    int srcA, int srcB, int qh, int swz)
{
    unsigned int pkH[4][2][2], pkL[4][2][2];
    f32x4 acc[4][2];
    // L1 (K=64, g only; corr/offset/flow enter via rank-5 f32 fix)
    zero_acc(acc);
    layer_l1(wl + W1OFS, Xhi, w, ln, q, swz, acc);
    epi_pack(acc, fws, 0, true, offsS, auxS, pkH, pkL, w, ln, q);
    // L2
    zero_acc(acc);
    layer_reg<128>(wl + W2OFS, pkH, pkL, srcA, srcB, qh, ln, q, swz, acc);
    epi_pack(acc, fws, 64, false, offsS, auxS, pkH, pkL, w, ln, q);
    // L3
    zero_acc(acc);
    layer_reg<128>(wl + W3OFS, pkH, pkL, srcA, srcB, qh, ln, q, swz, acc);
    epi_pack(acc, fws, 128, false, offsS, auxS, pkH, pkL, w, ln, q);
    // Lf: k 0-63 = x3 (reg exchange, hi+lo), k 64-127 = feat2d tile (F2 LDS, hi only)
    zero_acc(acc);
    layer_reg<256>(wl + WFOFS, pkH, pkL, srcA, srcB, qh, ln, q, swz, acc);
#pragma unroll
    for (int kt = 2; kt < 4; kt++) {
        const int kb = (kt * 32 + q * 8) * 2;
        short8 A[4];
#pragma unroll
        for (int mi = 0; mi < 4; mi++)
            A[mi] = *(const short8*)((const char*)(wl + WFOFS) + (mi * 16 + ln) * 256 + (kb ^ swz));
#pragma unroll
        for (int ni = 0; ni < 2; ni++) {
            const int nr = 32 * w + ni * 16 + ln;
            frag_u fh;
            fh.v = *(const short8*)&F2[nr * F2PITCH + (kt - 2) * 32 + q * 8];
            __builtin_amdgcn_s_setprio(1);
#pragma unroll
            for (int mi = 0; mi < 4; mi++)
                acc[mi][ni] = __builtin_amdgcn_mfma_f32_16x16x32_bf16(A[mi], fh.v, acc[mi][ni], 0, 0, 0);
            __builtin_amdgcn_s_setprio(0);
        }
    }
    // final epilogue -> out f32
#pragma unroll
    for (int mi = 0; mi < 4; mi++) {
        const float4 bias = *(const float4*)(fws + 192 + mi * 16 + q * 4);
#pragma unroll
        for (int ni = 0; ni < 2; ni++) {
#pragma unroll
            for (int r = 0; r < 4; r++) {
                float a = acc[mi][ni][r] + ((const float*)&bias)[r];
                a = fmaxf(a, 0.1f * a);
                const int m = mi * 16 + q * 4 + r;
                out[(size_t)(b * CH + m) * HW + p_base + 32 * w + ni * 16 + ln] = a;
            }
        }
    }
}

// ---------------- main fused kernel: 2-tile pipeline, weights in LDS, one barrier ---------
// LDS = 80,384 B -> still 2 blocks/CU. A-fragments now ds_read (swizzled) instead of
// 40KB/tile global streams that thrashed the 32KB L1.
__global__ __launch_bounds__(256, 2) void fuse(
    const float* __restrict__ feat2d, const float* __restrict__ lf2d,
    const int* __restrict__ nn,
    const unsigned short* __restrict__ wpk, const float* __restrict__ fws,
    const char* __restrict__ ptab,
    float* __restrict__ out)
{
    __shared__ unsigned short Xhi[NT * XPITCH];   // 18432 B (L1 gather stage)
    __shared__ unsigned short F2[NT * F2PITCH];   // 18432 B (feat2d tile bf16)
    __shared__ unsigned short Wl[20480];          // 40960 B (all weights, swizzled)
    __shared__ float offsS[2 * NT];               //  1024 B
    __shared__ float auxS[3 * NT];                //  1536 B

    const int tid = threadIdx.x;
    const int w = tid >> 6, lane = tid & 63;
    const int q = lane >> 4, ln = lane & 15;
    const int b = blockIdx.y;
    const int p0 = blockIdx.x * TW;
    const int n = 32 * w + (lane & 31);

    // bpermute byte addresses for the q-group exchange (src lanes (q&1)*2*16+ln, +16)
    const int srcA = (((lane >> 4) & 1) * 32 + ln) * 4;
    const int srcB = srcA + 64;
    const int qh = q >> 1;
    const int swz = (ln & 7) << 4;

    const int idx0 = nn[(size_t)b * HW + p0 + n];
    const int idx1 = nn[(size_t)b * HW + p0 + NT + n];

    pref_t P0, P1;
    tile_load(P0, feat2d, lf2d, ptab, b, p0, w, lane, idx0);   // HBM latency hides under wstage
    wstage(wpk, Wl, tid);
    __syncthreads();
    tile_stage(P0, F2, Xhi, w, lane);
    // prefetch tile 1 while tile 0 computes
    tile_load(P1, feat2d, lf2d, ptab, b, p0 + NT, w, lane, idx1);
    tile_corr(P0, F2, offsS, auxS, p0, w, lane);
    compute_tile(Xhi, F2, offsS, auxS, Wl, fws, out, b, p0, w, ln, q, srcA, srcB, qh, swz);
    tile_stage(P1, F2, Xhi, w, lane);
    tile_corr(P1, F2, offsS, auxS, p0 + NT, w, lane);
    compute_tile(Xhi, F2, offsS, auxS, Wl, fws, out, b, p0 + NT, w, ln, q, srcA, srcB, qh, swz);
}

// ---------------- fallback: used only if ws too small ----------------
__global__ __launch_bounds__(256) void fuse_slow(
    const float* __restrict__ feat2d, const float* __restrict__ lf2d,
    const float* __restrict__ xy, const float* __restrict__ feat3d,
    const float* __restrict__ lf3d, const int* __restrict__ nn,
    const float* __restrict__ w1, const float* __restrict__ b1,
    const float* __restrict__ w2, const float* __restrict__ b2,
    const float* __restrict__ w3, const float* __restrict__ b3,
    const float* __restrict__ wf, const float* __restrict__ bfv,
    float* __restrict__ out)
{
    const int p = blockIdx.x * 256 + threadIdx.x;
    const int b = blockIdx.y;
    const int idx = nn[(size_t)b * HW + p];
    const float* f3 = feat3d + (size_t)b * CH * NN + idx;
    float g[CH];
#pragma unroll
    for (int c = 0; c < CH; c++) g[c] = f3[(size_t)c * NN];
    const float fl3x = lf3d[(size_t)(b * 2 + 0) * NN + idx];
    const float fl3y = lf3d[(size_t)(b * 2 + 1) * NN + idx];
    const float xyx = xy[(size_t)(b * 2 + 0) * NN + idx];
    const float xyy = xy[(size_t)(b * 2 + 1) * NN + idx];
    const float* f2p = feat2d + (size_t)b * CH * HW + p;
    float corr = 0.f;
#pragma unroll
    for (int c = 0; c < CH; c++) corr += f2p[(size_t)c * HW] * g[c];
    corr *= (1.f / 64.f);
    float xin[69];
    xin[0] = corr;
    xin[1] = xyx - (float)(p & 255);
    xin[2] = xyy - (float)(p >> 8);
#pragma unroll
    for (int c = 0; c < CH; c++) xin[3 + c] = g[c];
    xin[67] = fl3x - lf2d[(size_t)(b * 2 + 0) * HW + p];
    xin[68] = fl3y - lf2d[(size_t)(b * 2 + 1) * HW + p];
    float x1[64], x2[64], x3[64], accv[64];
#pragma unroll
    for (int o = 0; o < 64; o++) {
        float a = b1[o];
#pragma unroll
        for (int k = 0; k < 69; k++) a += w1[o * 69 + k] * xin[k];
        x1[o] = (a >= 0.f) ? a : 0.1f * a;
    }
#pragma unroll
    for (int o = 0; o < 64; o++) {
        float a = b2[o];
#pragma unroll
        for (int k = 0; k < 64; k++) a += w2[o * 64 + k] * x1[k];
        x2[o] = (a >= 0.f) ? a : 0.1f * a;
    }
#pragma unroll
    for (int o = 0; o < 64; o++) {
        float a = b3[o];
#pragma unroll
        for (int k = 0; k < 64; k++) a += w3[o * 64 + k] * x2[k];
        x3[o] = (a >= 0.f) ? a : 0.1f * a;
    }
#pragma unroll
    for (int o = 0; o < 64; o++) {
        float a = bfv[o];
#pragma unroll
        for (int k = 0; k < 64; k++) a += wf[o * 128 + k] * x3[k];
        accv[o] = a;
    }
#pragma unroll
    for (int k = 0; k < 64; k++) {
        const float f = f2p[(size_t)k * HW];
#pragma unroll
        for (int o = 0; o < 64; o++) accv[o] += wf[o * 128 + 64 + k] * f;
    }
#pragma unroll
    for (int o = 0; o < 64; o++) {
        float a = accv[o];
        a = (a >= 0.f) ? a : 0.1f * a;
        out[(size_t)(b * CH + o) * HW + p] = a;
    }
}

extern "C" void kernel_launch(void* const* d_in, const int* in_sizes, int n_in,
                              void* d_out, int out_size, void* d_ws, size_t ws_size,
                              hipStream_t stream)
{
    const float* xy   = (const float*)d_in[0];
    const float* f2d  = (const float*)d_in[1];
    const float* f3d  = (const float*)d_in[2];
    const float* lf2d = (const float*)d_in[3];
    const float* lf3d = (const float*)d_in[4];
    const int*   nn   = (const int*)d_in[5];
    const float* w1 = (const float*)d_in[6];
    const float* b1 = (const float*)d_in[7];
    const float* w2 = (const float*)d_in[8];
    const float* b2 = (const float*)d_in[9];
    const float* w3 = (const float*)d_in[10];
    const float* b3 = (const float*)d_in[11];
    const float* wf = (const float*)d_in[12];
    const float* bf = (const float*)d_in[13];

    if (ws_size >= WS_NEED) {
        unsigned short* wpk = (unsigned short*)d_ws;
        float* fws = (float*)((char*)d_ws + FWS_BYTE);
        char* pt = (char*)d_ws + PTAB_BYTE;
        prep<<<dim3(NN / 64 + 5, BB), 256, 0, stream>>>(xy, f3d, lf3d,
                                                        w1, b1, w2, b2, w3, b3, wf, bf,
                                                        wpk, fws, pt);
        fuse<<<dim3(HW / TW, BB), 256, 0, stream>>>(f2d, lf2d, nn, wpk, fws, pt, (float*)d_out);
    } else {
        fuse_slow<<<dim3(HW / 256, BB), 256, 0, stream>>>(f2d, lf2d, xy, f3d, lf3d, nn,
                                                          w1, b1, w2, b2, w3, b3, wf, bf,
                                                          (float*)d_out);
    }
}